// Round 1
// baseline (667.989 us; speedup 1.0000x reference)
//
#include <hip/hip_runtime.h>

#define TT 1536
#define CC 1024
#define NH 16
#define HD 64
#define NL 2
#define NB 2
#define MM (NB*TT)  // 3072 rows total

typedef unsigned short u16;
typedef unsigned int u32;
typedef unsigned long long u64;
typedef __attribute__((ext_vector_type(8))) short short8v;
typedef __attribute__((ext_vector_type(4))) float f32x4;

__device__ __forceinline__ u16 f2bf(float f){
  u32 u = __float_as_uint(f);
  u32 r = (u + 0x7FFFu + ((u >> 16) & 1u)) >> 16;  // RNE
  return (u16)r;
}

__device__ __forceinline__ void gload_lds16(const void* g, void* l){
  __builtin_amdgcn_global_load_lds(
      (const __attribute__((address_space(1))) void*)g,
      (__attribute__((address_space(3))) void*)l, 16, 0, 0);
}

__device__ __forceinline__ f32x4 mfma16(short8v a, short8v b, f32x4 c){
  return __builtin_amdgcn_mfma_f32_16x16x32_bf16(a, b, c, 0, 0, 0);
}

// XOR swizzle for 128B-row LDS tiles (64 x u16 per row): spreads the
// 16-lane same-column read across 8 bank groups. Same helper for read+write.
__device__ __forceinline__ char* ldsw(void* base, int row, int colb){
  return (char*)base + row * 128 + (colb ^ ((row & 7) << 4));
}

// ---------------- f32 -> bf16 weight conversion ----------------
__global__ __launch_bounds__(256) void cvt_bf16_kernel(const float* __restrict__ in,
                                                       u16* __restrict__ out, int n4){
  int stride = gridDim.x * 256;
  for (int i = blockIdx.x * 256 + threadIdx.x; i < n4; i += stride){
    const float4 v = ((const float4*)in)[i];
    ushort4 o;
    o.x = f2bf(v.x); o.y = f2bf(v.y); o.z = f2bf(v.z); o.w = f2bf(v.w);
    ((ushort4*)out)[i] = o;
  }
}

// ---------------- mask precompute: 24 x u64 bit-words per row ----------------
__device__ __forceinline__ float fixc(float v){
  if (__builtin_isnan(v)) return 0.0f;
  if (__builtin_isinf(v)) return v > 0.0f ? 100.0f : -100.0f;
  return v;
}

__global__ __launch_bounds__(256) void mask_kernel(const float* __restrict__ coords,
                                                   u64* __restrict__ maskw){
  const int tid = threadIdx.x, wave = tid >> 6, lane = tid & 63;
  const int ri = blockIdx.x * 4 + wave;          // global row in [0, MM)
  const int b = ri / TT, i = ri - b * TT;
  const float* cp = coords + (size_t)ri * 3;
  const float cx = fixc(cp[0]), cy = fixc(cp[1]), cz = fixc(cp[2]);
  const int vi = i >> 8;                          // 256 tokens per view
  u64 allm = ~0ull;
  for (int ch = 0; ch < 24; ++ch){
    const int j = ch * 64 + lane;
    const float* cj = coords + ((size_t)b * TT + j) * 3;
    const float dx = cx - fixc(cj[0]);
    const float dy = cy - fixc(cj[1]);
    const float dz = cz - fixc(cj[2]);
    const float d2 = dx*dx + dy*dy + dz*dz;
    const bool masked = ((j >> 8) == vi) || (d2 > 100.0f);
    const u64 bal = __ballot(masked);
    if (lane == 0) maskw[(size_t)ri * 24 + ch] = bal;
    allm &= bal;
  }
  if (lane == 0 && allm == ~0ull){                // fully-masked row: unmask diagonal
    const size_t w = (size_t)ri * 24 + (i >> 6);
    maskw[w] &= ~(1ull << (i & 63));
  }
}

// ---------------- LayerNorm (f32 in -> bf16 or f32 out) ----------------
template<int OUTF>
__global__ __launch_bounds__(256) void ln_kernel(const float* __restrict__ x,
    const float* __restrict__ gw, const float* __restrict__ bw,
    u16* __restrict__ outb, float* __restrict__ outf){
  __shared__ float sred[4];
  const int tid = threadIdx.x, wave = tid >> 6, lane = tid & 63;
  const size_t row = blockIdx.x;
  const float4 v = *(const float4*)(x + row * CC + tid * 4);
  float s = v.x + v.y + v.z + v.w;
  #pragma unroll
  for (int o = 1; o < 64; o <<= 1) s += __shfl_xor(s, o, 64);
  if (lane == 0) sred[wave] = s;
  __syncthreads();
  const float mean = (sred[0] + sred[1] + sred[2] + sred[3]) * (1.0f / CC);
  __syncthreads();
  const float d0 = v.x - mean, d1 = v.y - mean, d2 = v.z - mean, d3 = v.w - mean;
  float q = d0*d0 + d1*d1 + d2*d2 + d3*d3;
  #pragma unroll
  for (int o = 1; o < 64; o <<= 1) q += __shfl_xor(q, o, 64);
  if (lane == 0) sred[wave] = q;
  __syncthreads();
  const float var = (sred[0] + sred[1] + sred[2] + sred[3]) * (1.0f / CC);
  const float rstd = rsqrtf(var + 1e-5f);
  const float4 g4 = *(const float4*)(gw + tid * 4);
  const float4 b4 = *(const float4*)(bw + tid * 4);
  const float y0 = d0 * rstd * g4.x + b4.x;
  const float y1 = d1 * rstd * g4.y + b4.y;
  const float y2 = d2 * rstd * g4.z + b4.z;
  const float y3 = d3 * rstd * g4.w + b4.w;
  if (OUTF){
    *(float4*)(outf + row * CC + tid * 4) = make_float4(y0, y1, y2, y3);
  } else {
    ushort4 o4; o4.x = f2bf(y0); o4.y = f2bf(y1); o4.z = f2bf(y2); o4.w = f2bf(y3);
    *(ushort4*)(outb + row * CC + tid * 4) = o4;
  }
}

// ---------------- NT GEMM: C[m,n] = sum_k A[m,k]*B[n,k], bf16 MFMA ----------------
// EPI 0: +bias -> bf16 out; EPI 1: +bias, gelu -> bf16 out; EPI 2: +bias +res -> f32 out
template<int EPI>
__global__ __launch_bounds__(256) void gemm_nt(const u16* __restrict__ A,
    const u16* __restrict__ Bw, const float* __restrict__ bias,
    const float* __restrict__ res, u16* __restrict__ outb, float* __restrict__ outf,
    int M, int N, int K){
  __shared__ u16 As[128][32];
  __shared__ u16 Bs[128][32];
  const int tid = threadIdx.x, wave = tid >> 6, lane = tid & 63;
  const int m0 = blockIdx.y * 128, n0 = blockIdx.x * 128;
  const int wr = wave >> 1, wc = wave & 1;
  f32x4 acc[4][4];
  #pragma unroll
  for (int a = 0; a < 4; ++a)
    #pragma unroll
    for (int bq = 0; bq < 4; ++bq){ f32x4 z = {0.f,0.f,0.f,0.f}; acc[a][bq] = z; }
  const int srow = wave * 16 + (lane >> 2);
  const int scol = (lane & 3) * 8;
  const u16* Ag = A + (size_t)m0 * K;
  const u16* Bg = Bw + (size_t)n0 * K;
  const int ar = lane & 15, ak = (lane >> 4) * 8;
  for (int k0 = 0; k0 < K; k0 += 32){
    #pragma unroll
    for (int l = 0; l < 2; ++l){
      gload_lds16(Ag + (size_t)(l*64 + srow) * K + k0 + scol,
                  (char*)(&As[0][0]) + (l*4 + wave) * 1024);
      gload_lds16(Bg + (size_t)(l*64 + srow) * K + k0 + scol,
                  (char*)(&Bs[0][0]) + (l*4 + wave) * 1024);
    }
    __syncthreads();
    short8v af[4], bfr[4];
    #pragma unroll
    for (int t = 0; t < 4; ++t){
      af[t]  = *(const short8v*)(&As[wr*64 + t*16 + ar][ak]);
      bfr[t] = *(const short8v*)(&Bs[wc*64 + t*16 + ar][ak]);
    }
    #pragma unroll
    for (int mi = 0; mi < 4; ++mi)
      #pragma unroll
      for (int ni = 0; ni < 4; ++ni)
        acc[mi][ni] = mfma16(af[mi], bfr[ni], acc[mi][ni]);
    __syncthreads();
  }
  const int cr = (lane >> 4) * 4, cl = lane & 15;
  #pragma unroll
  for (int ni = 0; ni < 4; ++ni){
    const int c = n0 + wc*64 + ni*16 + cl;
    const float bv = bias[c];
    #pragma unroll
    for (int mi = 0; mi < 4; ++mi){
      #pragma unroll
      for (int r = 0; r < 4; ++r){
        const size_t rr = (size_t)(m0 + wr*64 + mi*16 + cr + r);
        float v = acc[mi][ni][r] + bv;
        if constexpr (EPI == 1) v = 0.5f * v * (1.0f + erff(v * 0.70710678118654752f));
        if constexpr (EPI == 2) outf[rr * N + c] = v + res[rr * N + c];
        else outb[rr * N + c] = f2bf(v);
      }
    }
  }
}

// ---------------- Flash attention (bf16 MFMA, online softmax) ----------------
__global__ __launch_bounds__(256) void attn_kernel(const u16* __restrict__ qkv,
    const u64* __restrict__ maskw, u16* __restrict__ outp){
  __shared__ u16 Ks[64][64];      // K chunk, swizzled
  __shared__ u16 Vt[64][64];      // V^T chunk [d][j], swizzled
  __shared__ u16 Ps[4][16][64];   // per-wave P tile, swizzled
  const int tid = threadIdx.x, wave = tid >> 6, lane = tid & 63;
  const int b = blockIdx.y >> 4, h = blockIdx.y & 15;
  const int qb = blockIdx.x * 64;
  const int rs = 3 * CC;
  const int qrow = qb + wave * 16 + (lane & 15);
  const u16* qp = qkv + (size_t)(b * TT + qrow) * rs + h * HD + (lane >> 4) * 8;
  const short8v qf0 = *(const short8v*)qp;
  const short8v qf1 = *(const short8v*)(qp + 32);
  f32x4 o[4];
  float mrow[4], lsum[4];
  #pragma unroll
  for (int r = 0; r < 4; ++r){
    f32x4 z = {0.f,0.f,0.f,0.f}; o[r] = z;
    mrow[r] = -__builtin_huge_valf(); lsum[r] = 0.f;
  }
  const int rowbase = qb + wave * 16 + (lane >> 4) * 4;
  u16* psb = &Ps[wave][0][0];

  for (int j0 = 0; j0 < TT; j0 += 64){
    // --- stage K (global_load_lds, linear dest + inverse-swizzled source) ---
    #pragma unroll
    for (int l = 0; l < 2; ++l){
      const int off = (wave * 2 + l) * 1024;
      const int krow = (off >> 7) + (lane >> 3);
      const int kcolb = ((lane & 7) * 16) ^ ((krow & 7) << 4);
      gload_lds16(qkv + (size_t)(b * TT + j0 + krow) * rs + CC + h * HD + (kcolb >> 1),
                  (char*)(&Ks[0][0]) + off);
    }
    // --- stage V transposed: coalesced row loads, swizzled b128 write ---
    #pragma unroll
    for (int it = 0; it < 2; ++it){
      const int jc = it * 4 + wave;   // 8 j-columns per write
      u16 vv[8];
      #pragma unroll
      for (int e = 0; e < 8; ++e)
        vv[e] = qkv[(size_t)(b * TT + j0 + jc * 8 + e) * rs + 2 * CC + h * HD + lane];
      short8v sv;
      #pragma unroll
      for (int e = 0; e < 8; ++e) sv[e] = (short)vv[e];
      *(short8v*)ldsw(&Vt[0][0], lane, jc * 16) = sv;
    }
    __syncthreads();
    // --- S = Q K^T (per-wave 16x64) ---
    f32x4 S[4];
    #pragma unroll
    for (int jt = 0; jt < 4; ++jt){
      const int krw = jt * 16 + (lane & 15);
      const short8v k0 = *(const short8v*)ldsw(&Ks[0][0], krw, (lane >> 4) * 16);
      const short8v k1 = *(const short8v*)ldsw(&Ks[0][0], krw, 64 + (lane >> 4) * 16);
      f32x4 z = {0.f,0.f,0.f,0.f};
      z = mfma16(qf0, k0, z);
      z = mfma16(qf1, k1, z);
      S[jt] = z;
    }
    // --- mask + online softmax ---
    u64 mw[4];
    #pragma unroll
    for (int r = 0; r < 4; ++r)
      mw[r] = maskw[(size_t)(b * TT + rowbase + r) * 24 + (j0 >> 6)];
    float pv[4][4], cmax[4];
    #pragma unroll
    for (int r = 0; r < 4; ++r) cmax[r] = -__builtin_huge_valf();
    #pragma unroll
    for (int jt = 0; jt < 4; ++jt)
      #pragma unroll
      for (int r = 0; r < 4; ++r){
        float sv = S[jt][r] * 0.125f;
        const int bit = jt * 16 + (lane & 15);
        if ((mw[r] >> bit) & 1ull) sv = -__builtin_huge_valf();
        pv[jt][r] = sv;
        cmax[r] = fmaxf(cmax[r], sv);
      }
    #pragma unroll
    for (int r = 0; r < 4; ++r){
      #pragma unroll
      for (int sft = 1; sft < 16; sft <<= 1)
        cmax[r] = fmaxf(cmax[r], __shfl_xor(cmax[r], sft, 64));
    }
    float fac[4], psum[4];
    #pragma unroll
    for (int r = 0; r < 4; ++r){
      const float mn = fmaxf(mrow[r], cmax[r]);
      fac[r] = (mn == -__builtin_huge_valf()) ? 1.0f : __expf(mrow[r] - mn);
      mrow[r] = mn;
      psum[r] = 0.f;
    }
    #pragma unroll
    for (int jt = 0; jt < 4; ++jt)
      #pragma unroll
      for (int r = 0; r < 4; ++r){
        const float p = (pv[jt][r] == -__builtin_huge_valf()) ? 0.f : __expf(pv[jt][r] - mrow[r]);
        pv[jt][r] = p;
        psum[r] += p;
      }
    #pragma unroll
    for (int r = 0; r < 4; ++r){
      #pragma unroll
      for (int sft = 1; sft < 16; sft <<= 1)
        psum[r] += __shfl_xor(psum[r], sft, 64);
      lsum[r] = lsum[r] * fac[r] + psum[r];
    }
    #pragma unroll
    for (int dt = 0; dt < 4; ++dt){
      f32x4 t = o[dt];
      t[0] *= fac[0]; t[1] *= fac[1]; t[2] *= fac[2]; t[3] *= fac[3];
      o[dt] = t;
    }
    // --- P -> LDS (bf16, swizzled) ---
    #pragma unroll
    for (int jt = 0; jt < 4; ++jt)
      #pragma unroll
      for (int r = 0; r < 4; ++r)
        *(u16*)ldsw(psb, (lane >> 4) * 4 + r, 2 * (jt * 16 + (lane & 15))) = f2bf(pv[jt][r]);
    // --- O += P V ---
    short8v pf[2];
    #pragma unroll
    for (int kc = 0; kc < 2; ++kc)
      pf[kc] = *(const short8v*)ldsw(psb, lane & 15, kc * 64 + (lane >> 4) * 16);
    #pragma unroll
    for (int dt = 0; dt < 4; ++dt){
      #pragma unroll
      for (int kc = 0; kc < 2; ++kc){
        const short8v vf = *(const short8v*)ldsw(&Vt[0][0], dt*16 + (lane & 15),
                                                 kc * 64 + (lane >> 4) * 16);
        o[dt] = mfma16(pf[kc], vf, o[dt]);
      }
    }
    __syncthreads();
  }
  float linv[4];
  #pragma unroll
  for (int r = 0; r < 4; ++r) linv[r] = (lsum[r] > 0.f) ? 1.0f / lsum[r] : 0.f;
  #pragma unroll
  for (int dt = 0; dt < 4; ++dt)
    #pragma unroll
    for (int r = 0; r < 4; ++r)
      outp[(size_t)(b * TT + rowbase + r) * CC + h * HD + dt * 16 + (lane & 15)] =
          f2bf(o[dt][r] * linv[r]);
}

// ---------------- launcher ----------------
extern "C" void kernel_launch(void* const* d_in, const int* in_sizes, int n_in,
                              void* d_out, int out_size, void* d_ws, size_t ws_size,
                              hipStream_t stream){
  (void)in_sizes; (void)n_in; (void)out_size; (void)ws_size;
  const float* pos    = (const float*)d_in[0];
  const float* coords = (const float*)d_in[1];
  const float* ln1g   = (const float*)d_in[2];
  const float* ln1b   = (const float*)d_in[3];
  const float* qkvw   = (const float*)d_in[4];
  const float* qkvbi  = (const float*)d_in[5];
  const float* outw   = (const float*)d_in[6];
  const float* outbi  = (const float*)d_in[7];
  const float* ln2g   = (const float*)d_in[8];
  const float* ln2b   = (const float*)d_in[9];
  const float* w1     = (const float*)d_in[10];
  const float* b1     = (const float*)d_in[11];
  const float* w2     = (const float*)d_in[12];
  const float* b2     = (const float*)d_in[13];
  const float* ng     = (const float*)d_in[14];
  const float* nbb    = (const float*)d_in[15];

  char* wsp = (char*)d_ws;
  size_t off = 0;
  auto alloc = [&](size_t bytes)->void*{
    void* p = wsp + off; off += (bytes + 255) & ~(size_t)255; return p;
  };
  u16* qkvw_bf = (u16*)alloc((size_t)NL*3*CC*CC*sizeof(u16));
  u16* outw_bf = (u16*)alloc((size_t)NL*CC*CC*sizeof(u16));
  u16* w1_bf   = (u16*)alloc((size_t)NL*4*CC*CC*sizeof(u16));
  u16* w2_bf   = (u16*)alloc((size_t)NL*4*CC*CC*sizeof(u16));
  float* x     = (float*)alloc((size_t)MM*CC*sizeof(float));
  u16* xn      = (u16*)alloc((size_t)MM*CC*sizeof(u16));
  u16* qkvbuf  = (u16*)alloc((size_t)MM*4*CC*sizeof(u16)); // reused as FFN hidden
  u16* attnb   = (u16*)alloc((size_t)MM*CC*sizeof(u16));
  u64* maskw   = (u64*)alloc((size_t)MM*24*sizeof(u64));
  u16* hbuf = qkvbuf;

  auto cvt = [&](const float* s, u16* dst, size_t n){
    int n4 = (int)(n >> 2);
    int blocks = (n4 + 255) / 256; if (blocks > 4096) blocks = 4096;
    cvt_bf16_kernel<<<dim3(blocks), dim3(256), 0, stream>>>(s, dst, n4);
  };
  cvt(qkvw, qkvw_bf, (size_t)NL*3*CC*CC);
  cvt(outw, outw_bf, (size_t)NL*CC*CC);
  cvt(w1, w1_bf, (size_t)NL*4*CC*CC);
  cvt(w2, w2_bf, (size_t)NL*4*CC*CC);

  hipMemcpyAsync(x, pos, (size_t)MM*CC*sizeof(float), hipMemcpyDeviceToDevice, stream);
  mask_kernel<<<dim3(MM/4), dim3(256), 0, stream>>>(coords, maskw);

  for (int l = 0; l < NL; ++l){
    ln_kernel<0><<<dim3(MM), dim3(256), 0, stream>>>(x, ln1g + l*CC, ln1b + l*CC, xn, nullptr);
    gemm_nt<0><<<dim3(3*CC/128, MM/128), dim3(256), 0, stream>>>(
        xn, qkvw_bf + (size_t)l*3*CC*CC, qkvbi + l*3*CC, nullptr, qkvbuf, nullptr, MM, 3*CC, CC);
    attn_kernel<<<dim3(TT/64, NB*NH), dim3(256), 0, stream>>>(qkvbuf, maskw, attnb);
    gemm_nt<2><<<dim3(CC/128, MM/128), dim3(256), 0, stream>>>(
        attnb, outw_bf + (size_t)l*CC*CC, outbi + l*CC, x, nullptr, x, MM, CC, CC);
    ln_kernel<0><<<dim3(MM), dim3(256), 0, stream>>>(x, ln2g + l*CC, ln2b + l*CC, xn, nullptr);
    gemm_nt<1><<<dim3(4*CC/128, MM/128), dim3(256), 0, stream>>>(
        xn, w1_bf + (size_t)l*4*CC*CC, b1 + l*4*CC, nullptr, hbuf, nullptr, MM, 4*CC, CC);
    gemm_nt<2><<<dim3(CC/128, MM/128), dim3(256), 0, stream>>>(
        hbuf, w2_bf + (size_t)l*4*CC*CC, b2 + l*CC, x, nullptr, x, MM, CC, 4*CC);
  }
  ln_kernel<1><<<dim3(MM), dim3(256), 0, stream>>>(x, ng, nbb, nullptr, (float*)d_out);
}

// Round 3
// 622.245 us; speedup vs baseline: 1.0735x; 1.0735x over previous
//
#include <hip/hip_runtime.h>

#define TT 1536
#define CC 1024
#define NH 16
#define HD 64
#define NL 2
#define NB 2
#define MM (NB*TT)  // 3072 rows total

typedef unsigned short u16;
typedef unsigned int u32;
typedef unsigned long long u64;
typedef __attribute__((ext_vector_type(8))) short short8v;
typedef __attribute__((ext_vector_type(4))) float f32x4;

__device__ __forceinline__ u16 f2bf(float f){
  u32 u = __float_as_uint(f);
  u32 r = (u + 0x7FFFu + ((u >> 16) & 1u)) >> 16;  // RNE
  return (u16)r;
}

__device__ __forceinline__ u16 f2bfc(float f){    // cheap round (P in [0,1])
  return (u16)((__float_as_uint(f) + 0x8000u) >> 16);
}

__device__ __forceinline__ void gload_lds16(const void* g, void* l){
  __builtin_amdgcn_global_load_lds(
      (const __attribute__((address_space(1))) void*)g,
      (__attribute__((address_space(3))) void*)l, 16, 0, 0);
}

__device__ __forceinline__ f32x4 mfma16(short8v a, short8v b, f32x4 c){
  return __builtin_amdgcn_mfma_f32_16x16x32_bf16(a, b, c, 0, 0, 0);
}

// XOR swizzle for 128B-row LDS tiles (64 x u16 per row).
__device__ __forceinline__ char* ldsw(void* base, int row, int colb){
  return (char*)base + row * 128 + (colb ^ ((row & 7) << 4));
}

// exact bf16 * 0.125 (power of two)
__device__ __forceinline__ short bf16_eighth(short x){
  float f = __uint_as_float(((u32)(u16)x) << 16) * 0.125f;
  return (short)(u16)(__float_as_uint(f) >> 16);
}

// ---------------- f32 -> bf16 weight conversion ----------------
__global__ __launch_bounds__(256) void cvt_bf16_kernel(const float* __restrict__ in,
                                                       u16* __restrict__ out, int n4){
  int stride = gridDim.x * 256;
  for (int i = blockIdx.x * 256 + threadIdx.x; i < n4; i += stride){
    const float4 v = ((const float4*)in)[i];
    ushort4 o;
    o.x = f2bf(v.x); o.y = f2bf(v.y); o.z = f2bf(v.z); o.w = f2bf(v.w);
    ((ushort4*)out)[i] = o;
  }
}

// ---------------- mask precompute: 24 x u64 bit-words per row ----------------
__device__ __forceinline__ float fixc(float v){
  if (__builtin_isnan(v)) return 0.0f;
  if (__builtin_isinf(v)) return v > 0.0f ? 100.0f : -100.0f;
  return v;
}

__global__ __launch_bounds__(256) void mask_kernel(const float* __restrict__ coords,
                                                   u64* __restrict__ maskw){
  const int tid = threadIdx.x, wave = tid >> 6, lane = tid & 63;
  const int ri = blockIdx.x * 4 + wave;          // global row in [0, MM)
  const int b = ri / TT, i = ri - b * TT;
  const float* cp = coords + (size_t)ri * 3;
  const float cx = fixc(cp[0]), cy = fixc(cp[1]), cz = fixc(cp[2]);
  const int vi = i >> 8;                          // 256 tokens per view
  u64 allm = ~0ull;
  for (int ch = 0; ch < 24; ++ch){
    const int j = ch * 64 + lane;
    const float* cj = coords + ((size_t)b * TT + j) * 3;
    const float dx = cx - fixc(cj[0]);
    const float dy = cy - fixc(cj[1]);
    const float dz = cz - fixc(cj[2]);
    const float d2 = dx*dx + dy*dy + dz*dz;
    const bool masked = ((j >> 8) == vi) || (d2 > 100.0f);
    const u64 bal = __ballot(masked);
    if (lane == 0) maskw[(size_t)ri * 24 + ch] = bal;
    allm &= bal;
  }
  if (lane == 0 && allm == ~0ull){                // fully-masked row: unmask diagonal
    const size_t w = (size_t)ri * 24 + (i >> 6);
    maskw[w] &= ~(1ull << (i & 63));
  }
}

// ---------------- LayerNorm (f32 in -> bf16 or f32 out) ----------------
template<int OUTF>
__global__ __launch_bounds__(256) void ln_kernel(const float* __restrict__ x,
    const float* __restrict__ gw, const float* __restrict__ bw,
    u16* __restrict__ outb, float* __restrict__ outf){
  __shared__ float sred[4];
  const int tid = threadIdx.x, wave = tid >> 6, lane = tid & 63;
  const size_t row = blockIdx.x;
  const float4 v = *(const float4*)(x + row * CC + tid * 4);
  float s = v.x + v.y + v.z + v.w;
  #pragma unroll
  for (int o = 1; o < 64; o <<= 1) s += __shfl_xor(s, o, 64);
  if (lane == 0) sred[wave] = s;
  __syncthreads();
  const float mean = (sred[0] + sred[1] + sred[2] + sred[3]) * (1.0f / CC);
  __syncthreads();
  const float d0 = v.x - mean, d1 = v.y - mean, d2 = v.z - mean, d3 = v.w - mean;
  float q = d0*d0 + d1*d1 + d2*d2 + d3*d3;
  #pragma unroll
  for (int o = 1; o < 64; o <<= 1) q += __shfl_xor(q, o, 64);
  if (lane == 0) sred[wave] = q;
  __syncthreads();
  const float var = (sred[0] + sred[1] + sred[2] + sred[3]) * (1.0f / CC);
  const float rstd = rsqrtf(var + 1e-5f);
  const float4 g4 = *(const float4*)(gw + tid * 4);
  const float4 b4 = *(const float4*)(bw + tid * 4);
  const float y0 = d0 * rstd * g4.x + b4.x;
  const float y1 = d1 * rstd * g4.y + b4.y;
  const float y2 = d2 * rstd * g4.z + b4.z;
  const float y3 = d3 * rstd * g4.w + b4.w;
  if (OUTF){
    *(float4*)(outf + row * CC + tid * 4) = make_float4(y0, y1, y2, y3);
  } else {
    ushort4 o4; o4.x = f2bf(y0); o4.y = f2bf(y1); o4.z = f2bf(y2); o4.w = f2bf(y3);
    *(ushort4*)(outb + row * CC + tid * 4) = o4;
  }
}

// ---------------- NT GEMM: C[m,n] = sum_k A[m,k]*B[n,k], bf16 MFMA ----------------
// EPI 0: +bias -> bf16 out; EPI 1: +bias, gelu -> bf16 out; EPI 2: +bias +res -> f32 out
template<int EPI>
__global__ __launch_bounds__(256) void gemm_nt(const u16* __restrict__ A,
    const u16* __restrict__ Bw, const float* __restrict__ bias,
    const float* __restrict__ res, u16* __restrict__ outb, float* __restrict__ outf,
    int M, int N, int K){
  __shared__ u16 As[128][32];
  __shared__ u16 Bs[128][32];
  const int tid = threadIdx.x, wave = tid >> 6, lane = tid & 63;
  // bijective XCD swizzle (m204): consecutive orig blocks land on the same XCD
  const int gx = gridDim.x;
  const int nwg = gx * gridDim.y;
  const int orig = blockIdx.y * gx + blockIdx.x;
  const int qq = nwg >> 3, rr = nwg & 7;
  const int xcd = orig & 7, pos = orig >> 3;
  const int wg = (xcd < rr ? xcd * (qq + 1) : rr * (qq + 1) + (xcd - rr) * qq) + pos;
  const int m0 = (wg / gx) * 128, n0 = (wg % gx) * 128;
  const int wr = wave >> 1, wc = wave & 1;
  f32x4 acc[4][4];
  #pragma unroll
  for (int a = 0; a < 4; ++a)
    #pragma unroll
    for (int bq = 0; bq < 4; ++bq){ f32x4 z = {0.f,0.f,0.f,0.f}; acc[a][bq] = z; }
  const int srow = wave * 16 + (lane >> 2);
  const int scol = (lane & 3) * 8;
  const u16* Ag = A + (size_t)m0 * K;
  const u16* Bg = Bw + (size_t)n0 * K;
  const int ar = lane & 15, ak = (lane >> 4) * 8;
  for (int k0 = 0; k0 < K; k0 += 32){
    #pragma unroll
    for (int l = 0; l < 2; ++l){
      gload_lds16(Ag + (size_t)(l*64 + srow) * K + k0 + scol,
                  (char*)(&As[0][0]) + (l*4 + wave) * 1024);
      gload_lds16(Bg + (size_t)(l*64 + srow) * K + k0 + scol,
                  (char*)(&Bs[0][0]) + (l*4 + wave) * 1024);
    }
    __syncthreads();
    short8v af[4], bfr[4];
    #pragma unroll
    for (int t = 0; t < 4; ++t){
      af[t]  = *(const short8v*)(&As[wr*64 + t*16 + ar][ak]);
      bfr[t] = *(const short8v*)(&Bs[wc*64 + t*16 + ar][ak]);
    }
    #pragma unroll
    for (int mi = 0; mi < 4; ++mi)
      #pragma unroll
      for (int ni = 0; ni < 4; ++ni)
        acc[mi][ni] = mfma16(af[mi], bfr[ni], acc[mi][ni]);
    __syncthreads();
  }
  const int cr = (lane >> 4) * 4, cl = lane & 15;
  #pragma unroll
  for (int ni = 0; ni < 4; ++ni){
    const int c = n0 + wc*64 + ni*16 + cl;
    const float bv = bias[c];
    #pragma unroll
    for (int mi = 0; mi < 4; ++mi){
      #pragma unroll
      for (int r = 0; r < 4; ++r){
        const size_t rr2 = (size_t)(m0 + wr*64 + mi*16 + cr + r);
        float v = acc[mi][ni][r] + bv;
        if constexpr (EPI == 1) v = 0.5f * v * (1.0f + erff(v * 0.70710678118654752f));
        if constexpr (EPI == 2) outf[rr2 * N + c] = v + res[rr2 * N + c];
        else outb[rr2 * N + c] = f2bf(v);
      }
    }
  }
}

// ---------------- Flash attention v2: swapped QK^T (lane-local P row),
// double-buffered K/V staging, 2-phase pipeline ----------------
__global__ __launch_bounds__(256) void attn_kernel(const u16* __restrict__ qkv,
    const u64* __restrict__ maskw, u16* __restrict__ outp){
  __shared__ u16 Ks[2][64][64];   // K chunk, swizzled rows
  __shared__ u16 Vt[2][64][64];   // V^T chunk [d][j], swizzled rows
  __shared__ u16 Ps[4][16][64];   // per-wave P tile [q_local][key], swizzled
  const int tid = threadIdx.x, wave = tid >> 6, lane = tid & 63;
  const int b = blockIdx.y >> 4, h = blockIdx.y & 15;
  const int qb = blockIdx.x * 64;
  const int rs = 3 * CC;
  const int g4 = lane >> 4;        // 0..3
  const int l15 = lane & 15;
  const int qrow = qb + wave * 16 + l15;

  // Q fragment (A/B-layout: row/col = l15, k = g4*8..), pre-scaled by 1/8
  const u16* qp = qkv + (size_t)(b * TT + qrow) * rs + h * HD + g4 * 8;
  short8v qf0, qf1;
  {
    const short8v r0 = *(const short8v*)qp;
    const short8v r1 = *(const short8v*)(qp + 32);
    #pragma unroll
    for (int e = 0; e < 8; ++e){ qf0[e] = bf16_eighth(r0[e]); qf1[e] = bf16_eighth(r1[e]); }
  }

  f32x4 o[4];
  #pragma unroll
  for (int dt = 0; dt < 4; ++dt){ f32x4 z = {0.f,0.f,0.f,0.f}; o[dt] = z; }
  float m_r = -1e30f, l_r = 0.f;   // per-lane: running max/sum of row q = qrow

  u16* psb = &Ps[wave][0][0];
  const u64* mrow_p = maskw + (size_t)(b * TT + qrow) * 24;

  auto stageK = [&](int t, int buf){
    const int j0 = t * 64;
    #pragma unroll
    for (int l = 0; l < 2; ++l){
      const int off = (wave * 2 + l) * 1024;             // wave-uniform
      const int krow = (off >> 7) + (lane >> 3);
      const int kcolb = ((lane & 7) * 16) ^ ((krow & 7) << 4);  // inverse-swizzled source
      gload_lds16(qkv + (size_t)(b * TT + j0 + krow) * rs + CC + h * HD + (kcolb >> 1),
                  (char*)(&Ks[buf][0][0]) + off);
    }
  };
  u16 vv[16];
  auto loadV = [&](int t){
    const int j0 = t * 64;
    #pragma unroll
    for (int it = 0; it < 2; ++it){
      const int jc = it * 4 + wave;
      #pragma unroll
      for (int e = 0; e < 8; ++e)
        vv[it*8+e] = qkv[(size_t)(b * TT + j0 + jc * 8 + e) * rs + 2 * CC + h * HD + lane];
    }
  };
  auto writeV = [&](int buf){
    #pragma unroll
    for (int it = 0; it < 2; ++it){
      const int jc = it * 4 + wave;
      short8v sv;
      #pragma unroll
      for (int e = 0; e < 8; ++e) sv[e] = (short)vv[it*8+e];
      *(short8v*)ldsw(&Vt[buf][0][0], lane, jc * 16) = sv;
    }
  };

  // prologue: stage chunk 0 into buf 0
  loadV(0);
  stageK(0, 0);
  writeV(0);
  __syncthreads();

  for (int t = 0; t < TT / 64; ++t){
    const int cur = t & 1;
    const bool pf = (t < TT / 64 - 1);
    if (pf){ loadV(t + 1); stageK(t + 1, cur ^ 1); }

    const u64 mw = mrow_p[t];

    // --- S^T = (K/8... actually Q/8) : D[m=key_local, n=q] via swapped mfma ---
    const char* Kc = (const char*)&Ks[cur][0][0];
    f32x4 S[4];
    #pragma unroll
    for (int jt = 0; jt < 4; ++jt){
      const short8v k0 = *(const short8v*)ldsw((void*)Kc, jt*16 + l15, g4 * 16);
      const short8v k1 = *(const short8v*)ldsw((void*)Kc, jt*16 + l15, 64 + g4 * 16);
      f32x4 z = {0.f,0.f,0.f,0.f};
      z = mfma16(k0, qf0, z);
      z = mfma16(k1, qf1, z);
      S[jt] = z;   // lane holds keys jt*16 + g4*4 + r of row q = qrow
    }

    // --- mask + per-row (lane-local) online softmax ---
    float ps[16]; u32 pmask = 0;
    float cmax = -1e30f;
    #pragma unroll
    for (int jt = 0; jt < 4; ++jt){
      const u32 mj = (u32)(mw >> (jt * 16 + g4 * 4)) & 0xFu;
      #pragma unroll
      for (int r = 0; r < 4; ++r){
        float s = S[jt][r];
        s = ((mj >> r) & 1u) ? -1e30f : s;
        ps[jt*4+r] = s;
        cmax = fmaxf(cmax, s);
      }
      pmask |= mj << (jt * 4);
    }
    cmax = fmaxf(cmax, __shfl_xor(cmax, 16));
    cmax = fmaxf(cmax, __shfl_xor(cmax, 32));
    const float mnew = fmaxf(m_r, cmax);
    const float fac = __expf(m_r - mnew);   // branch-free: 0/0 case -> exp(0)=1
    m_r = mnew;
    float psum = 0.f;
    #pragma unroll
    for (int i = 0; i < 16; ++i){
      const float p = ((pmask >> i) & 1u) ? 0.f : __expf(ps[i] - mnew);
      ps[i] = p; psum += p;
    }
    psum += __shfl_xor(psum, 16);
    psum += __shfl_xor(psum, 32);
    l_r = l_r * fac + psum;

    // broadcast fac of rows g4*4+r (held at lanes 0..15) and rescale O
    float fr4[4];
    #pragma unroll
    for (int r = 0; r < 4; ++r) fr4[r] = __shfl(fac, g4 * 4 + r);
    #pragma unroll
    for (int dt = 0; dt < 4; ++dt){
      f32x4 tt = o[dt];
      tt[0] *= fr4[0]; tt[1] *= fr4[1]; tt[2] *= fr4[2]; tt[3] *= fr4[3];
      o[dt] = tt;
    }

    // --- P -> LDS: 4 consecutive keys per group -> b64 writes ---
    #pragma unroll
    for (int jt = 0; jt < 4; ++jt){
      ushort4 pk;
      pk.x = f2bfc(ps[jt*4+0]); pk.y = f2bfc(ps[jt*4+1]);
      pk.z = f2bfc(ps[jt*4+2]); pk.w = f2bfc(ps[jt*4+3]);
      *(ushort4*)ldsw(psb, l15, jt * 32 + g4 * 8) = pk;
    }

    // --- O += P V ---
    short8v pA[2];
    #pragma unroll
    for (int kc = 0; kc < 2; ++kc)
      pA[kc] = *(const short8v*)ldsw(psb, l15, kc * 64 + g4 * 16);
    char* Vc = (char*)&Vt[cur][0][0];
    #pragma unroll
    for (int dt = 0; dt < 4; ++dt){
      #pragma unroll
      for (int kc = 0; kc < 2; ++kc){
        const short8v vf = *(const short8v*)ldsw(Vc, dt*16 + l15, kc * 64 + g4 * 16);
        o[dt] = mfma16(pA[kc], vf, o[dt]);
      }
    }

    if (pf) writeV(cur ^ 1);
    __syncthreads();
  }

  const float linv = (l_r > 0.f) ? 1.0f / l_r : 0.f;
  float lr4[4];
  #pragma unroll
  for (int r = 0; r < 4; ++r) lr4[r] = __shfl(linv, g4 * 4 + r);
  #pragma unroll
  for (int dt = 0; dt < 4; ++dt)
    #pragma unroll
    for (int r = 0; r < 4; ++r)
      outp[(size_t)(b * TT + qb + wave * 16 + g4 * 4 + r) * CC + h * HD + dt * 16 + l15] =
          f2bf(o[dt][r] * lr4[r]);
}

// ---------------- launcher ----------------
extern "C" void kernel_launch(void* const* d_in, const int* in_sizes, int n_in,
                              void* d_out, int out_size, void* d_ws, size_t ws_size,
                              hipStream_t stream){
  (void)in_sizes; (void)n_in; (void)out_size; (void)ws_size;
  const float* pos    = (const float*)d_in[0];
  const float* coords = (const float*)d_in[1];
  const float* ln1g   = (const float*)d_in[2];
  const float* ln1b   = (const float*)d_in[3];
  const float* qkvw   = (const float*)d_in[4];
  const float* qkvbi  = (const float*)d_in[5];
  const float* outw   = (const float*)d_in[6];
  const float* outbi  = (const float*)d_in[7];
  const float* ln2g   = (const float*)d_in[8];
  const float* ln2b   = (const float*)d_in[9];
  const float* w1     = (const float*)d_in[10];
  const float* b1     = (const float*)d_in[11];
  const float* w2     = (const float*)d_in[12];
  const float* b2     = (const float*)d_in[13];
  const float* ng     = (const float*)d_in[14];
  const float* nbb    = (const float*)d_in[15];

  char* wsp = (char*)d_ws;
  size_t off = 0;
  auto alloc = [&](size_t bytes)->void*{
    void* p = wsp + off; off += (bytes + 255) & ~(size_t)255; return p;
  };
  u16* qkvw_bf = (u16*)alloc((size_t)NL*3*CC*CC*sizeof(u16));
  u16* outw_bf = (u16*)alloc((size_t)NL*CC*CC*sizeof(u16));
  u16* w1_bf   = (u16*)alloc((size_t)NL*4*CC*CC*sizeof(u16));
  u16* w2_bf   = (u16*)alloc((size_t)NL*4*CC*CC*sizeof(u16));
  float* x     = (float*)alloc((size_t)MM*CC*sizeof(float));
  u16* xn      = (u16*)alloc((size_t)MM*CC*sizeof(u16));
  u16* qkvbuf  = (u16*)alloc((size_t)MM*4*CC*sizeof(u16)); // reused as FFN hidden
  u16* attnb   = (u16*)alloc((size_t)MM*CC*sizeof(u16));
  u64* maskw   = (u64*)alloc((size_t)MM*24*sizeof(u64));
  u16* hbuf = qkvbuf;

  auto cvt = [&](const float* s, u16* dst, size_t n){
    int n4 = (int)(n >> 2);
    int blocks = (n4 + 255) / 256; if (blocks > 4096) blocks = 4096;
    cvt_bf16_kernel<<<dim3(blocks), dim3(256), 0, stream>>>(s, dst, n4);
  };
  cvt(qkvw, qkvw_bf, (size_t)NL*3*CC*CC);
  cvt(outw, outw_bf, (size_t)NL*CC*CC);
  cvt(w1, w1_bf, (size_t)NL*4*CC*CC);
  cvt(w2, w2_bf, (size_t)NL*4*CC*CC);

  hipMemcpyAsync(x, pos, (size_t)MM*CC*sizeof(float), hipMemcpyDeviceToDevice, stream);
  mask_kernel<<<dim3(MM/4), dim3(256), 0, stream>>>(coords, maskw);

  for (int l = 0; l < NL; ++l){
    ln_kernel<0><<<dim3(MM), dim3(256), 0, stream>>>(x, ln1g + l*CC, ln1b + l*CC, xn, nullptr);
    gemm_nt<0><<<dim3(3*CC/128, MM/128), dim3(256), 0, stream>>>(
        xn, qkvw_bf + (size_t)l*3*CC*CC, qkvbi + l*3*CC, nullptr, qkvbuf, nullptr, MM, 3*CC, CC);
    attn_kernel<<<dim3(TT/64, NB*NH), dim3(256), 0, stream>>>(qkvbuf, maskw, attnb);
    gemm_nt<2><<<dim3(CC/128, MM/128), dim3(256), 0, stream>>>(
        attnb, outw_bf + (size_t)l*CC*CC, outbi + l*CC, x, nullptr, x, MM, CC, CC);
    ln_kernel<0><<<dim3(MM), dim3(256), 0, stream>>>(x, ln2g + l*CC, ln2b + l*CC, xn, nullptr);
    gemm_nt<1><<<dim3(4*CC/128, MM/128), dim3(256), 0, stream>>>(
        xn, w1_bf + (size_t)l*4*CC*CC, b1 + l*4*CC, nullptr, hbuf, nullptr, MM, 4*CC, CC);
    gemm_nt<2><<<dim3(CC/128, MM/128), dim3(256), 0, stream>>>(
        hbuf, w2_bf + (size_t)l*4*CC*CC, b2 + l*CC, x, nullptr, x, MM, CC, 4*CC);
  }
  ln_kernel<1><<<dim3(MM), dim3(256), 0, stream>>>(x, ng, nbb, nullptr, (float*)d_out);
}

// Round 4
// 612.342 us; speedup vs baseline: 1.0909x; 1.0162x over previous
//
#include <hip/hip_runtime.h>

#define TT 1536
#define CC 1024
#define NH 16
#define HD 64
#define NL 2
#define NB 2
#define MM (NB*TT)  // 3072 rows total

typedef unsigned short u16;
typedef unsigned int u32;
typedef unsigned long long u64;
typedef __attribute__((ext_vector_type(8))) short short8v;
typedef __attribute__((ext_vector_type(4))) float f32x4;

__device__ __forceinline__ u16 f2bf(float f){
  u32 u = __float_as_uint(f);
  u32 r = (u + 0x7FFFu + ((u >> 16) & 1u)) >> 16;  // RNE
  return (u16)r;
}

__device__ __forceinline__ u16 f2bfc(float f){    // cheap round (P in [0,1])
  return (u16)((__float_as_uint(f) + 0x8000u) >> 16);
}

__device__ __forceinline__ void gload_lds16(const void* g, void* l){
  __builtin_amdgcn_global_load_lds(
      (const __attribute__((address_space(1))) void*)g,
      (__attribute__((address_space(3))) void*)l, 16, 0, 0);
}

__device__ __forceinline__ f32x4 mfma16(short8v a, short8v b, f32x4 c){
  return __builtin_amdgcn_mfma_f32_16x16x32_bf16(a, b, c, 0, 0, 0);
}

// XOR swizzle for 128B-row LDS tiles (64 x u16 per row).
__device__ __forceinline__ char* ldsw(void* base, int row, int colb){
  return (char*)base + row * 128 + (colb ^ ((row & 7) << 4));
}

// exact bf16 * 0.125 (power of two)
__device__ __forceinline__ short bf16_eighth(short x){
  float f = __uint_as_float(((u32)(u16)x) << 16) * 0.125f;
  return (short)(u16)(__float_as_uint(f) >> 16);
}

// ---------------- f32 -> bf16 weight conversion ----------------
__global__ __launch_bounds__(256) void cvt_bf16_kernel(const float* __restrict__ in,
                                                       u16* __restrict__ out, int n4){
  int stride = gridDim.x * 256;
  for (int i = blockIdx.x * 256 + threadIdx.x; i < n4; i += stride){
    const float4 v = ((const float4*)in)[i];
    ushort4 o;
    o.x = f2bf(v.x); o.y = f2bf(v.y); o.z = f2bf(v.z); o.w = f2bf(v.w);
    ((ushort4*)out)[i] = o;
  }
}

// ---------------- mask precompute: 24 x u64 bit-words per row ----------------
__device__ __forceinline__ float fixc(float v){
  if (__builtin_isnan(v)) return 0.0f;
  if (__builtin_isinf(v)) return v > 0.0f ? 100.0f : -100.0f;
  return v;
}

__global__ __launch_bounds__(256) void mask_kernel(const float* __restrict__ coords,
                                                   u64* __restrict__ maskw){
  const int tid = threadIdx.x, wave = tid >> 6, lane = tid & 63;
  const int ri = blockIdx.x * 4 + wave;          // global row in [0, MM)
  const int b = ri / TT, i = ri - b * TT;
  const float* cp = coords + (size_t)ri * 3;
  const float cx = fixc(cp[0]), cy = fixc(cp[1]), cz = fixc(cp[2]);
  const int vi = i >> 8;                          // 256 tokens per view
  u64 allm = ~0ull;
  for (int ch = 0; ch < 24; ++ch){
    const int j = ch * 64 + lane;
    const float* cj = coords + ((size_t)b * TT + j) * 3;
    const float dx = cx - fixc(cj[0]);
    const float dy = cy - fixc(cj[1]);
    const float dz = cz - fixc(cj[2]);
    const float d2 = dx*dx + dy*dy + dz*dz;
    const bool masked = ((j >> 8) == vi) || (d2 > 100.0f);
    const u64 bal = __ballot(masked);
    if (lane == 0) maskw[(size_t)ri * 24 + ch] = bal;
    allm &= bal;
  }
  if (lane == 0 && allm == ~0ull){                // fully-masked row: unmask diagonal
    const size_t w = (size_t)ri * 24 + (i >> 6);
    maskw[w] &= ~(1ull << (i & 63));
  }
}

// ---------------- LayerNorm (f32 in -> bf16 or f32 out) ----------------
template<int OUTF>
__global__ __launch_bounds__(256) void ln_kernel(const float* __restrict__ x,
    const float* __restrict__ gw, const float* __restrict__ bw,
    u16* __restrict__ outb, float* __restrict__ outf){
  __shared__ float sred[4];
  const int tid = threadIdx.x, wave = tid >> 6, lane = tid & 63;
  const size_t row = blockIdx.x;
  const float4 v = *(const float4*)(x + row * CC + tid * 4);
  float s = v.x + v.y + v.z + v.w;
  #pragma unroll
  for (int o = 1; o < 64; o <<= 1) s += __shfl_xor(s, o, 64);
  if (lane == 0) sred[wave] = s;
  __syncthreads();
  const float mean = (sred[0] + sred[1] + sred[2] + sred[3]) * (1.0f / CC);
  __syncthreads();
  const float d0 = v.x - mean, d1 = v.y - mean, d2 = v.z - mean, d3 = v.w - mean;
  float q = d0*d0 + d1*d1 + d2*d2 + d3*d3;
  #pragma unroll
  for (int o = 1; o < 64; o <<= 1) q += __shfl_xor(q, o, 64);
  if (lane == 0) sred[wave] = q;
  __syncthreads();
  const float var = (sred[0] + sred[1] + sred[2] + sred[3]) * (1.0f / CC);
  const float rstd = rsqrtf(var + 1e-5f);
  const float4 g4 = *(const float4*)(gw + tid * 4);
  const float4 b4 = *(const float4*)(bw + tid * 4);
  const float y0 = d0 * rstd * g4.x + b4.x;
  const float y1 = d1 * rstd * g4.y + b4.y;
  const float y2 = d2 * rstd * g4.z + b4.z;
  const float y3 = d3 * rstd * g4.w + b4.w;
  if (OUTF){
    *(float4*)(outf + row * CC + tid * 4) = make_float4(y0, y1, y2, y3);
  } else {
    ushort4 o4; o4.x = f2bf(y0); o4.y = f2bf(y1); o4.z = f2bf(y2); o4.w = f2bf(y3);
    *(ushort4*)(outb + row * CC + tid * 4) = o4;
  }
}

// ---------------- NT GEMM v2: 128x128 tile, 8 waves, BK=64, double-buffered,
// counted-vmcnt 2-phase pipeline (loads stay in flight across raw barriers) ----
// EPI 0: +bias -> bf16; EPI 1: +bias,gelu -> bf16; EPI 2: +bias +res -> f32
template<int EPI>
__global__ __launch_bounds__(512, 4) void gemm_nt(const u16* __restrict__ A,
    const u16* __restrict__ Bw, const float* __restrict__ bias,
    const float* __restrict__ res, u16* __restrict__ outb, float* __restrict__ outf,
    int M, int N, int K){
  __shared__ u16 As[2][128][64];
  __shared__ u16 Bs[2][128][64];
  const int tid = threadIdx.x, wave = tid >> 6, lane = tid & 63;
  // bijective XCD swizzle (m204)
  const int gx = gridDim.x;
  const int nwg = gx * gridDim.y;
  const int orig = blockIdx.y * gx + blockIdx.x;
  const int qq = nwg >> 3, rm = nwg & 7;
  const int xcd = orig & 7, pos = orig >> 3;
  const int wg = (xcd < rm ? xcd * (qq + 1) : rm * (qq + 1) + (xcd - rm) * qq) + pos;
  const int m0 = (wg / gx) * 128, n0 = (wg % gx) * 128;
  const int wr = wave >> 1, wc = wave & 1;   // 4x2 wave grid; per-wave out 32x64
  f32x4 acc[2][4];
  #pragma unroll
  for (int mi = 0; mi < 2; ++mi)
    #pragma unroll
    for (int ni = 0; ni < 4; ++ni){ f32x4 z = {0.f,0.f,0.f,0.f}; acc[mi][ni] = z; }

  const u16* Ag = A + (size_t)m0 * K;
  const u16* Bg = Bw + (size_t)n0 * K;
  // staging: round l (0/1), wave w covers rows l*64 + w*8 + (lane>>3), col bytes (lane&7)*16
  const int srow0 = wave * 8 + (lane >> 3);
  const int scole = (lane & 7) * 8;          // element col
  auto stage = [&](int buf, int k0){
    char* ab = (char*)&As[buf][0][0];
    char* bb = (char*)&Bs[buf][0][0];
    #pragma unroll
    for (int l = 0; l < 2; ++l){
      const size_t goff = (size_t)(l*64 + srow0) * K + k0 + scole;
      const int loff = (l*8 + wave) * 1024;
      gload_lds16(Ag + goff, ab + loff);
      gload_lds16(Bg + goff, bb + loff);
    }
  };

  const int NT = K >> 6;
  stage(0, 0);
  stage(1, 64);

  const int ar = lane & 15, akb = (lane >> 4) * 16;  // frag row, k-chunk byte off
  for (int t = 0; t < NT; ++t){
    const int cur = t & 1;
    // wait tile t's loads (leave t+1's 4 in flight), then sync all waves
    if (t + 1 < NT) asm volatile("s_waitcnt vmcnt(4)" ::: "memory");
    else            asm volatile("s_waitcnt vmcnt(0)" ::: "memory");
    __builtin_amdgcn_s_barrier();
    // register fragments for this K-tile
    const char* ab = (const char*)&As[cur][0][0];
    const char* bb = (const char*)&Bs[cur][0][0];
    short8v af[2][2], bf[4][2];
    #pragma unroll
    for (int ks = 0; ks < 2; ++ks){
      #pragma unroll
      for (int mi = 0; mi < 2; ++mi)
        af[mi][ks] = *(const short8v*)(ab + (wr*32 + mi*16 + ar)*128 + ks*64 + akb);
      #pragma unroll
      for (int ni = 0; ni < 4; ++ni)
        bf[ni][ks] = *(const short8v*)(bb + (wc*64 + ni*16 + ar)*128 + ks*64 + akb);
    }
    asm volatile("s_waitcnt lgkmcnt(0)" ::: "memory");
    __builtin_amdgcn_sched_barrier(0);
    __builtin_amdgcn_s_barrier();          // all waves done reading buf cur
    if (t + 2 < NT) stage(cur, (t + 2) * 64);  // overwrite cur with tile t+2
    __builtin_amdgcn_s_setprio(1);
    #pragma unroll
    for (int ks = 0; ks < 2; ++ks)
      #pragma unroll
      for (int mi = 0; mi < 2; ++mi)
        #pragma unroll
        for (int ni = 0; ni < 4; ++ni)
          acc[mi][ni] = mfma16(af[mi][ks], bf[ni][ks], acc[mi][ni]);
    __builtin_amdgcn_s_setprio(0);
  }

  const int cr = (lane >> 4) * 4, cl = lane & 15;
  #pragma unroll
  for (int ni = 0; ni < 4; ++ni){
    const int c = n0 + wc*64 + ni*16 + cl;
    const float bv = bias[c];
    #pragma unroll
    for (int mi = 0; mi < 2; ++mi){
      #pragma unroll
      for (int r = 0; r < 4; ++r){
        const size_t rr2 = (size_t)(m0 + wr*32 + mi*16 + cr + r);
        float v = acc[mi][ni][r] + bv;
        if constexpr (EPI == 1) v = 0.5f * v * (1.0f + erff(v * 0.70710678118654752f));
        if constexpr (EPI == 2) outf[rr2 * N + c] = v + res[rr2 * N + c];
        else outb[rr2 * N + c] = f2bf(v);
      }
    }
  }
}

// ---------------- Flash attention v2: swapped QK^T (lane-local P row),
// double-buffered K/V staging, 2-phase pipeline ----------------
__global__ __launch_bounds__(256) void attn_kernel(const u16* __restrict__ qkv,
    const u64* __restrict__ maskw, u16* __restrict__ outp){
  __shared__ u16 Ks[2][64][64];   // K chunk, swizzled rows
  __shared__ u16 Vt[2][64][64];   // V^T chunk [d][j], swizzled rows
  __shared__ u16 Ps[4][16][64];   // per-wave P tile [q_local][key], swizzled
  const int tid = threadIdx.x, wave = tid >> 6, lane = tid & 63;
  const int b = blockIdx.y >> 4, h = blockIdx.y & 15;
  const int qb = blockIdx.x * 64;
  const int rs = 3 * CC;
  const int g4 = lane >> 4;        // 0..3
  const int l15 = lane & 15;
  const int qrow = qb + wave * 16 + l15;

  // Q fragment (A/B-layout: row/col = l15, k = g4*8..), pre-scaled by 1/8
  const u16* qp = qkv + (size_t)(b * TT + qrow) * rs + h * HD + g4 * 8;
  short8v qf0, qf1;
  {
    const short8v r0 = *(const short8v*)qp;
    const short8v r1 = *(const short8v*)(qp + 32);
    #pragma unroll
    for (int e = 0; e < 8; ++e){ qf0[e] = bf16_eighth(r0[e]); qf1[e] = bf16_eighth(r1[e]); }
  }

  f32x4 o[4];
  #pragma unroll
  for (int dt = 0; dt < 4; ++dt){ f32x4 z = {0.f,0.f,0.f,0.f}; o[dt] = z; }
  float m_r = -1e30f, l_r = 0.f;   // per-lane: running max/sum of row q = qrow

  u16* psb = &Ps[wave][0][0];
  const u64* mrow_p = maskw + (size_t)(b * TT + qrow) * 24;

  auto stageK = [&](int t, int buf){
    const int j0 = t * 64;
    #pragma unroll
    for (int l = 0; l < 2; ++l){
      const int off = (wave * 2 + l) * 1024;             // wave-uniform
      const int krow = (off >> 7) + (lane >> 3);
      const int kcolb = ((lane & 7) * 16) ^ ((krow & 7) << 4);  // inverse-swizzled source
      gload_lds16(qkv + (size_t)(b * TT + j0 + krow) * rs + CC + h * HD + (kcolb >> 1),
                  (char*)(&Ks[buf][0][0]) + off);
    }
  };
  u16 vv[16];
  auto loadV = [&](int t){
    const int j0 = t * 64;
    #pragma unroll
    for (int it = 0; it < 2; ++it){
      const int jc = it * 4 + wave;
      #pragma unroll
      for (int e = 0; e < 8; ++e)
        vv[it*8+e] = qkv[(size_t)(b * TT + j0 + jc * 8 + e) * rs + 2 * CC + h * HD + lane];
    }
  };
  auto writeV = [&](int buf){
    #pragma unroll
    for (int it = 0; it < 2; ++it){
      const int jc = it * 4 + wave;
      short8v sv;
      #pragma unroll
      for (int e = 0; e < 8; ++e) sv[e] = (short)vv[it*8+e];
      *(short8v*)ldsw(&Vt[buf][0][0], lane, jc * 16) = sv;
    }
  };

  // prologue: stage chunk 0 into buf 0
  loadV(0);
  stageK(0, 0);
  writeV(0);
  __syncthreads();

  for (int t = 0; t < TT / 64; ++t){
    const int cur = t & 1;
    const bool pf = (t < TT / 64 - 1);
    if (pf){ loadV(t + 1); stageK(t + 1, cur ^ 1); }

    const u64 mw = mrow_p[t];

    // --- S^T: D[m=key_local, n=q] via swapped mfma ---
    const char* Kc = (const char*)&Ks[cur][0][0];
    f32x4 S[4];
    #pragma unroll
    for (int jt = 0; jt < 4; ++jt){
      const short8v k0 = *(const short8v*)ldsw((void*)Kc, jt*16 + l15, g4 * 16);
      const short8v k1 = *(const short8v*)ldsw((void*)Kc, jt*16 + l15, 64 + g4 * 16);
      f32x4 z = {0.f,0.f,0.f,0.f};
      z = mfma16(k0, qf0, z);
      z = mfma16(k1, qf1, z);
      S[jt] = z;   // lane holds keys jt*16 + g4*4 + r of row q = qrow
    }

    // --- mask + per-row (lane-local) online softmax ---
    float ps[16]; u32 pmask = 0;
    float cmax = -1e30f;
    #pragma unroll
    for (int jt = 0; jt < 4; ++jt){
      const u32 mj = (u32)(mw >> (jt * 16 + g4 * 4)) & 0xFu;
      #pragma unroll
      for (int r = 0; r < 4; ++r){
        float s = S[jt][r];
        s = ((mj >> r) & 1u) ? -1e30f : s;
        ps[jt*4+r] = s;
        cmax = fmaxf(cmax, s);
      }
      pmask |= mj << (jt * 4);
    }
    cmax = fmaxf(cmax, __shfl_xor(cmax, 16));
    cmax = fmaxf(cmax, __shfl_xor(cmax, 32));
    const float mnew = fmaxf(m_r, cmax);
    const float fac = __expf(m_r - mnew);   // branch-free
    m_r = mnew;
    float psum = 0.f;
    #pragma unroll
    for (int i = 0; i < 16; ++i){
      const float p = ((pmask >> i) & 1u) ? 0.f : __expf(ps[i] - mnew);
      ps[i] = p; psum += p;
    }
    psum += __shfl_xor(psum, 16);
    psum += __shfl_xor(psum, 32);
    l_r = l_r * fac + psum;

    // broadcast fac of rows g4*4+r (held at lanes 0..15) and rescale O
    float fr4[4];
    #pragma unroll
    for (int r = 0; r < 4; ++r) fr4[r] = __shfl(fac, g4 * 4 + r);
    #pragma unroll
    for (int dt = 0; dt < 4; ++dt){
      f32x4 tt = o[dt];
      tt[0] *= fr4[0]; tt[1] *= fr4[1]; tt[2] *= fr4[2]; tt[3] *= fr4[3];
      o[dt] = tt;
    }

    // --- P -> LDS: 4 consecutive keys per group -> b64 writes ---
    #pragma unroll
    for (int jt = 0; jt < 4; ++jt){
      ushort4 pk;
      pk.x = f2bfc(ps[jt*4+0]); pk.y = f2bfc(ps[jt*4+1]);
      pk.z = f2bfc(ps[jt*4+2]); pk.w = f2bfc(ps[jt*4+3]);
      *(ushort4*)ldsw(psb, l15, jt * 32 + g4 * 8) = pk;
    }

    // --- O += P V ---
    short8v pA[2];
    #pragma unroll
    for (int kc = 0; kc < 2; ++kc)
      pA[kc] = *(const short8v*)ldsw(psb, l15, kc * 64 + g4 * 16);
    char* Vc = (char*)&Vt[cur][0][0];
    #pragma unroll
    for (int dt = 0; dt < 4; ++dt){
      #pragma unroll
      for (int kc = 0; kc < 2; ++kc){
        const short8v vf = *(const short8v*)ldsw(Vc, dt*16 + l15, kc * 64 + g4 * 16);
        o[dt] = mfma16(pA[kc], vf, o[dt]);
      }
    }

    if (pf) writeV(cur ^ 1);
    __syncthreads();
  }

  const float linv = (l_r > 0.f) ? 1.0f / l_r : 0.f;
  float lr4[4];
  #pragma unroll
  for (int r = 0; r < 4; ++r) lr4[r] = __shfl(linv, g4 * 4 + r);
  #pragma unroll
  for (int dt = 0; dt < 4; ++dt)
    #pragma unroll
    for (int r = 0; r < 4; ++r)
      outp[(size_t)(b * TT + qb + wave * 16 + g4 * 4 + r) * CC + h * HD + dt * 16 + l15] =
          f2bf(o[dt][r] * lr4[r]);
}

// ---------------- launcher ----------------
extern "C" void kernel_launch(void* const* d_in, const int* in_sizes, int n_in,
                              void* d_out, int out_size, void* d_ws, size_t ws_size,
                              hipStream_t stream){
  (void)in_sizes; (void)n_in; (void)out_size; (void)ws_size;
  const float* pos    = (const float*)d_in[0];
  const float* coords = (const float*)d_in[1];
  const float* ln1g   = (const float*)d_in[2];
  const float* ln1b   = (const float*)d_in[3];
  const float* qkvw   = (const float*)d_in[4];
  const float* qkvbi  = (const float*)d_in[5];
  const float* outw   = (const float*)d_in[6];
  const float* outbi  = (const float*)d_in[7];
  const float* ln2g   = (const float*)d_in[8];
  const float* ln2b   = (const float*)d_in[9];
  const float* w1     = (const float*)d_in[10];
  const float* b1     = (const float*)d_in[11];
  const float* w2     = (const float*)d_in[12];
  const float* b2     = (const float*)d_in[13];
  const float* ng     = (const float*)d_in[14];
  const float* nbb    = (const float*)d_in[15];

  char* wsp = (char*)d_ws;
  size_t off = 0;
  auto alloc = [&](size_t bytes)->void*{
    void* p = wsp + off; off += (bytes + 255) & ~(size_t)255; return p;
  };
  u16* qkvw_bf = (u16*)alloc((size_t)NL*3*CC*CC*sizeof(u16));
  u16* outw_bf = (u16*)alloc((size_t)NL*CC*CC*sizeof(u16));
  u16* w1_bf   = (u16*)alloc((size_t)NL*4*CC*CC*sizeof(u16));
  u16* w2_bf   = (u16*)alloc((size_t)NL*4*CC*CC*sizeof(u16));
  float* x     = (float*)alloc((size_t)MM*CC*sizeof(float));
  u16* xn      = (u16*)alloc((size_t)MM*CC*sizeof(u16));
  u16* qkvbuf  = (u16*)alloc((size_t)MM*4*CC*sizeof(u16)); // reused as FFN hidden
  u16* attnb   = (u16*)alloc((size_t)MM*CC*sizeof(u16));
  u64* maskw   = (u64*)alloc((size_t)MM*24*sizeof(u64));
  u16* hbuf = qkvbuf;

  auto cvt = [&](const float* s, u16* dst, size_t n){
    int n4 = (int)(n >> 2);
    int blocks = (n4 + 255) / 256; if (blocks > 4096) blocks = 4096;
    cvt_bf16_kernel<<<dim3(blocks), dim3(256), 0, stream>>>(s, dst, n4);
  };
  cvt(qkvw, qkvw_bf, (size_t)NL*3*CC*CC);
  cvt(outw, outw_bf, (size_t)NL*CC*CC);
  cvt(w1, w1_bf, (size_t)NL*4*CC*CC);
  cvt(w2, w2_bf, (size_t)NL*4*CC*CC);

  hipMemcpyAsync(x, pos, (size_t)MM*CC*sizeof(float), hipMemcpyDeviceToDevice, stream);
  mask_kernel<<<dim3(MM/4), dim3(256), 0, stream>>>(coords, maskw);

  for (int l = 0; l < NL; ++l){
    ln_kernel<0><<<dim3(MM), dim3(256), 0, stream>>>(x, ln1g + l*CC, ln1b + l*CC, xn, nullptr);
    gemm_nt<0><<<dim3(3*CC/128, MM/128), dim3(512), 0, stream>>>(
        xn, qkvw_bf + (size_t)l*3*CC*CC, qkvbi + l*3*CC, nullptr, qkvbuf, nullptr, MM, 3*CC, CC);
    attn_kernel<<<dim3(TT/64, NB*NH), dim3(256), 0, stream>>>(qkvbuf, maskw, attnb);
    gemm_nt<2><<<dim3(CC/128, MM/128), dim3(512), 0, stream>>>(
        attnb, outw_bf + (size_t)l*CC*CC, outbi + l*CC, x, nullptr, x, MM, CC, CC);
    ln_kernel<0><<<dim3(MM), dim3(256), 0, stream>>>(x, ln2g + l*CC, ln2b + l*CC, xn, nullptr);
    gemm_nt<1><<<dim3(4*CC/128, MM/128), dim3(512), 0, stream>>>(
        xn, w1_bf + (size_t)l*4*CC*CC, b1 + l*4*CC, nullptr, hbuf, nullptr, MM, 4*CC, CC);
    gemm_nt<2><<<dim3(CC/128, MM/128), dim3(512), 0, stream>>>(
        hbuf, w2_bf + (size_t)l*4*CC*CC, b2 + l*CC, x, nullptr, x, MM, CC, 4*CC);
  }
  ln_kernel<1><<<dim3(MM), dim3(256), 0, stream>>>(x, ng, nbb, nullptr, (float*)d_out);
}

// Round 5
// 477.572 us; speedup vs baseline: 1.3987x; 1.2822x over previous
//
#include <hip/hip_runtime.h>

#define TT 1536
#define CC 1024
#define NH 16
#define HD 64
#define NL 2
#define NB 2
#define MM (NB*TT)  // 3072 rows total

typedef unsigned short u16;
typedef unsigned int u32;
typedef unsigned long long u64;
typedef __attribute__((ext_vector_type(8))) short short8v;
typedef __attribute__((ext_vector_type(4))) float f32x4;

__device__ __forceinline__ u16 f2bf(float f){
  u32 u = __float_as_uint(f);
  u32 r = (u + 0x7FFFu + ((u >> 16) & 1u)) >> 16;  // RNE
  return (u16)r;
}

__device__ __forceinline__ u16 f2bfc(float f){    // cheap round (P in [0,1])
  return (u16)((__float_as_uint(f) + 0x8000u) >> 16);
}

__device__ __forceinline__ void gload_lds16(const void* g, void* l){
  __builtin_amdgcn_global_load_lds(
      (const __attribute__((address_space(1))) void*)g,
      (__attribute__((address_space(3))) void*)l, 16, 0, 0);
}

__device__ __forceinline__ f32x4 mfma16(short8v a, short8v b, f32x4 c){
  return __builtin_amdgcn_mfma_f32_16x16x32_bf16(a, b, c, 0, 0, 0);
}

// XOR swizzle for 128B-row LDS tiles (64 x u16 per row).
__device__ __forceinline__ char* ldsw(void* base, int row, int colb){
  return (char*)base + row * 128 + (colb ^ ((row & 7) << 4));
}

// exact bf16 * 0.125 (power of two)
__device__ __forceinline__ short bf16_eighth(short x){
  float f = __uint_as_float(((u32)(u16)x) << 16) * 0.125f;
  return (short)(u16)(__float_as_uint(f) >> 16);
}

// ---------------- f32 -> bf16 weight conversion ----------------
__global__ __launch_bounds__(256) void cvt_bf16_kernel(const float* __restrict__ in,
                                                       u16* __restrict__ out, int n4){
  int stride = gridDim.x * 256;
  for (int i = blockIdx.x * 256 + threadIdx.x; i < n4; i += stride){
    const float4 v = ((const float4*)in)[i];
    ushort4 o;
    o.x = f2bf(v.x); o.y = f2bf(v.y); o.z = f2bf(v.z); o.w = f2bf(v.w);
    ((ushort4*)out)[i] = o;
  }
}

// ---------------- mask precompute: 24 x u64 bit-words per row ----------------
__device__ __forceinline__ float fixc(float v){
  if (__builtin_isnan(v)) return 0.0f;
  if (__builtin_isinf(v)) return v > 0.0f ? 100.0f : -100.0f;
  return v;
}

__global__ __launch_bounds__(256) void mask_kernel(const float* __restrict__ coords,
                                                   u64* __restrict__ maskw){
  const int tid = threadIdx.x, wave = tid >> 6, lane = tid & 63;
  const int ri = blockIdx.x * 4 + wave;          // global row in [0, MM)
  const int b = ri / TT, i = ri - b * TT;
  const float* cp = coords + (size_t)ri * 3;
  const float cx = fixc(cp[0]), cy = fixc(cp[1]), cz = fixc(cp[2]);
  const int vi = i >> 8;                          // 256 tokens per view
  u64 allm = ~0ull;
  for (int ch = 0; ch < 24; ++ch){
    const int j = ch * 64 + lane;
    const float* cj = coords + ((size_t)b * TT + j) * 3;
    const float dx = cx - fixc(cj[0]);
    const float dy = cy - fixc(cj[1]);
    const float dz = cz - fixc(cj[2]);
    const float d2 = dx*dx + dy*dy + dz*dz;
    const bool masked = ((j >> 8) == vi) || (d2 > 100.0f);
    const u64 bal = __ballot(masked);
    if (lane == 0) maskw[(size_t)ri * 24 + ch] = bal;
    allm &= bal;
  }
  if (lane == 0 && allm == ~0ull){                // fully-masked row: unmask diagonal
    const size_t w = (size_t)ri * 24 + (i >> 6);
    maskw[w] &= ~(1ull << (i & 63));
  }
}

// ---------------- LayerNorm (f32 in -> bf16 or f32 out) ----------------
template<int OUTF>
__global__ __launch_bounds__(256) void ln_kernel(const float* __restrict__ x,
    const float* __restrict__ gw, const float* __restrict__ bw,
    u16* __restrict__ outb, float* __restrict__ outf){
  __shared__ float sred[4];
  const int tid = threadIdx.x, wave = tid >> 6, lane = tid & 63;
  const size_t row = blockIdx.x;
  const float4 v = *(const float4*)(x + row * CC + tid * 4);
  float s = v.x + v.y + v.z + v.w;
  #pragma unroll
  for (int o = 1; o < 64; o <<= 1) s += __shfl_xor(s, o, 64);
  if (lane == 0) sred[wave] = s;
  __syncthreads();
  const float mean = (sred[0] + sred[1] + sred[2] + sred[3]) * (1.0f / CC);
  __syncthreads();
  const float d0 = v.x - mean, d1 = v.y - mean, d2 = v.z - mean, d3 = v.w - mean;
  float q = d0*d0 + d1*d1 + d2*d2 + d3*d3;
  #pragma unroll
  for (int o = 1; o < 64; o <<= 1) q += __shfl_xor(q, o, 64);
  if (lane == 0) sred[wave] = q;
  __syncthreads();
  const float var = (sred[0] + sred[1] + sred[2] + sred[3]) * (1.0f / CC);
  const float rstd = rsqrtf(var + 1e-5f);
  const float4 g4 = *(const float4*)(gw + tid * 4);
  const float4 b4 = *(const float4*)(bw + tid * 4);
  const float y0 = d0 * rstd * g4.x + b4.x;
  const float y1 = d1 * rstd * g4.y + b4.y;
  const float y2 = d2 * rstd * g4.z + b4.z;
  const float y3 = d3 * rstd * g4.w + b4.w;
  if (OUTF){
    *(float4*)(outf + row * CC + tid * 4) = make_float4(y0, y1, y2, y3);
  } else {
    ushort4 o4; o4.x = f2bf(y0); o4.y = f2bf(y1); o4.z = f2bf(y2); o4.w = f2bf(y3);
    *(ushort4*)(outb + row * CC + tid * 4) = o4;
  }
}

// ---------------- NT GEMM v3: 128x128 tile, 8 waves, BK=64, double-buffered,
// counted-vmcnt 2-phase pipeline + T2 XOR-swizzled LDS (pre-swizzled global
// source for the linear global_load_lds dest, swizzled ds_read addrs) --------
// EPI 0: +bias -> bf16; EPI 1: +bias,gelu -> bf16; EPI 2: +bias +res -> f32
template<int EPI>
__global__ __launch_bounds__(512, 4) void gemm_nt(const u16* __restrict__ A,
    const u16* __restrict__ Bw, const float* __restrict__ bias,
    const float* __restrict__ res, u16* __restrict__ outb, float* __restrict__ outf,
    int M, int N, int K){
  __shared__ u16 As[2][128][64];
  __shared__ u16 Bs[2][128][64];
  const int tid = threadIdx.x, wave = tid >> 6, lane = tid & 63;
  // bijective XCD swizzle (m204)
  const int gx = gridDim.x;
  const int nwg = gx * gridDim.y;
  const int orig = blockIdx.y * gx + blockIdx.x;
  const int qq = nwg >> 3, rm = nwg & 7;
  const int xcd = orig & 7, pos = orig >> 3;
  const int wg = (xcd < rm ? xcd * (qq + 1) : rm * (qq + 1) + (xcd - rm) * qq) + pos;
  const int m0 = (wg / gx) * 128, n0 = (wg % gx) * 128;
  const int wr = wave >> 1, wc = wave & 1;   // 4x2 wave grid; per-wave out 32x64
  f32x4 acc[2][4];
  #pragma unroll
  for (int mi = 0; mi < 2; ++mi)
    #pragma unroll
    for (int ni = 0; ni < 4; ++ni){ f32x4 z = {0.f,0.f,0.f,0.f}; acc[mi][ni] = z; }

  const u16* Ag = A + (size_t)m0 * K;
  const u16* Bg = Bw + (size_t)n0 * K;
  // staging: LDS dest is LINEAR (global_load_lds constraint); the swizzle is
  // applied by permuting the global SOURCE column. Staged row has row&7 ==
  // lane>>3, so source elem col = 8*((lane&7) ^ (lane>>3)).  [rule #21]
  const int srow0 = wave * 8 + (lane >> 3);
  const int scole = ((lane & 7) ^ (lane >> 3)) * 8;
  auto stage = [&](int buf, int k0){
    char* ab = (char*)&As[buf][0][0];
    char* bb = (char*)&Bs[buf][0][0];
    #pragma unroll
    for (int l = 0; l < 2; ++l){
      const size_t goff = (size_t)(l*64 + srow0) * K + k0 + scole;
      const int loff = (l*8 + wave) * 1024;
      gload_lds16(Ag + goff, ab + loff);
      gload_lds16(Bg + goff, bb + loff);
    }
  };

  const int NT = K >> 6;
  stage(0, 0);
  stage(1, 64);

  const int ar = lane & 15, akb = (lane >> 4) * 16;  // frag row, k-chunk byte off
  const int rsw = (ar & 7) << 4;                     // read-side XOR (row&7 == ar&7)
  for (int t = 0; t < NT; ++t){
    const int cur = t & 1;
    // wait tile t's loads (leave t+1's 4 in flight), then sync all waves
    if (t + 1 < NT) asm volatile("s_waitcnt vmcnt(4)" ::: "memory");
    else            asm volatile("s_waitcnt vmcnt(0)" ::: "memory");
    __builtin_amdgcn_s_barrier();
    // register fragments for this K-tile (swizzled read addresses)
    const char* ab = (const char*)&As[cur][0][0];
    const char* bb = (const char*)&Bs[cur][0][0];
    short8v af[2][2], bf[4][2];
    #pragma unroll
    for (int ks = 0; ks < 2; ++ks){
      const int cb = (ks*64 + akb) ^ rsw;
      #pragma unroll
      for (int mi = 0; mi < 2; ++mi)
        af[mi][ks] = *(const short8v*)(ab + (wr*32 + mi*16 + ar)*128 + cb);
      #pragma unroll
      for (int ni = 0; ni < 4; ++ni)
        bf[ni][ks] = *(const short8v*)(bb + (wc*64 + ni*16 + ar)*128 + cb);
    }
    asm volatile("s_waitcnt lgkmcnt(0)" ::: "memory");
    __builtin_amdgcn_sched_barrier(0);
    __builtin_amdgcn_s_barrier();          // all waves done reading buf cur
    if (t + 2 < NT) stage(cur, (t + 2) * 64);  // overwrite cur with tile t+2
    __builtin_amdgcn_s_setprio(1);
    #pragma unroll
    for (int ks = 0; ks < 2; ++ks)
      #pragma unroll
      for (int mi = 0; mi < 2; ++mi)
        #pragma unroll
        for (int ni = 0; ni < 4; ++ni)
          acc[mi][ni] = mfma16(af[mi][ks], bf[ni][ks], acc[mi][ni]);
    __builtin_amdgcn_s_setprio(0);
  }

  const int cr = (lane >> 4) * 4, cl = lane & 15;
  #pragma unroll
  for (int ni = 0; ni < 4; ++ni){
    const int c = n0 + wc*64 + ni*16 + cl;
    const float bv = bias[c];
    #pragma unroll
    for (int mi = 0; mi < 2; ++mi){
      #pragma unroll
      for (int r = 0; r < 4; ++r){
        const size_t rr2 = (size_t)(m0 + wr*32 + mi*16 + cr + r);
        float v = acc[mi][ni][r] + bv;
        if constexpr (EPI == 1) v = 0.5f * v * (1.0f + erff(v * 0.70710678118654752f));
        if constexpr (EPI == 2) outf[rr2 * N + c] = v + res[rr2 * N + c];
        else outb[rr2 * N + c] = f2bf(v);
      }
    }
  }
}

// ---------------- Flash attention v2: swapped QK^T (lane-local P row),
// double-buffered K/V staging, 2-phase pipeline ----------------
__global__ __launch_bounds__(256) void attn_kernel(const u16* __restrict__ qkv,
    const u64* __restrict__ maskw, u16* __restrict__ outp){
  __shared__ u16 Ks[2][64][64];   // K chunk, swizzled rows
  __shared__ u16 Vt[2][64][64];   // V^T chunk [d][j], swizzled rows
  __shared__ u16 Ps[4][16][64];   // per-wave P tile [q_local][key], swizzled
  const int tid = threadIdx.x, wave = tid >> 6, lane = tid & 63;
  const int b = blockIdx.y >> 4, h = blockIdx.y & 15;
  const int qb = blockIdx.x * 64;
  const int rs = 3 * CC;
  const int g4 = lane >> 4;        // 0..3
  const int l15 = lane & 15;
  const int qrow = qb + wave * 16 + l15;

  // Q fragment (A/B-layout: row/col = l15, k = g4*8..), pre-scaled by 1/8
  const u16* qp = qkv + (size_t)(b * TT + qrow) * rs + h * HD + g4 * 8;
  short8v qf0, qf1;
  {
    const short8v r0 = *(const short8v*)qp;
    const short8v r1 = *(const short8v*)(qp + 32);
    #pragma unroll
    for (int e = 0; e < 8; ++e){ qf0[e] = bf16_eighth(r0[e]); qf1[e] = bf16_eighth(r1[e]); }
  }

  f32x4 o[4];
  #pragma unroll
  for (int dt = 0; dt < 4; ++dt){ f32x4 z = {0.f,0.f,0.f,0.f}; o[dt] = z; }
  float m_r = -1e30f, l_r = 0.f;   // per-lane: running max/sum of row q = qrow

  u16* psb = &Ps[wave][0][0];
  const u64* mrow_p = maskw + (size_t)(b * TT + qrow) * 24;

  auto stageK = [&](int t, int buf){
    const int j0 = t * 64;
    #pragma unroll
    for (int l = 0; l < 2; ++l){
      const int off = (wave * 2 + l) * 1024;             // wave-uniform
      const int krow = (off >> 7) + (lane >> 3);
      const int kcolb = ((lane & 7) * 16) ^ ((krow & 7) << 4);  // inverse-swizzled source
      gload_lds16(qkv + (size_t)(b * TT + j0 + krow) * rs + CC + h * HD + (kcolb >> 1),
                  (char*)(&Ks[buf][0][0]) + off);
    }
  };
  u16 vv[16];
  auto loadV = [&](int t){
    const int j0 = t * 64;
    #pragma unroll
    for (int it = 0; it < 2; ++it){
      const int jc = it * 4 + wave;
      #pragma unroll
      for (int e = 0; e < 8; ++e)
        vv[it*8+e] = qkv[(size_t)(b * TT + j0 + jc * 8 + e) * rs + 2 * CC + h * HD + lane];
    }
  };
  auto writeV = [&](int buf){
    #pragma unroll
    for (int it = 0; it < 2; ++it){
      const int jc = it * 4 + wave;
      short8v sv;
      #pragma unroll
      for (int e = 0; e < 8; ++e) sv[e] = (short)vv[it*8+e];
      *(short8v*)ldsw(&Vt[buf][0][0], lane, jc * 16) = sv;
    }
  };

  // prologue: stage chunk 0 into buf 0
  loadV(0);
  stageK(0, 0);
  writeV(0);
  __syncthreads();

  for (int t = 0; t < TT / 64; ++t){
    const int cur = t & 1;
    const bool pf = (t < TT / 64 - 1);
    if (pf){ loadV(t + 1); stageK(t + 1, cur ^ 1); }

    const u64 mw = mrow_p[t];

    // --- S^T: D[m=key_local, n=q] via swapped mfma ---
    const char* Kc = (const char*)&Ks[cur][0][0];
    f32x4 S[4];
    #pragma unroll
    for (int jt = 0; jt < 4; ++jt){
      const short8v k0 = *(const short8v*)ldsw((void*)Kc, jt*16 + l15, g4 * 16);
      const short8v k1 = *(const short8v*)ldsw((void*)Kc, jt*16 + l15, 64 + g4 * 16);
      f32x4 z = {0.f,0.f,0.f,0.f};
      z = mfma16(k0, qf0, z);
      z = mfma16(k1, qf1, z);
      S[jt] = z;   // lane holds keys jt*16 + g4*4 + r of row q = qrow
    }

    // --- mask + per-row (lane-local) online softmax ---
    float ps[16]; u32 pmask = 0;
    float cmax = -1e30f;
    #pragma unroll
    for (int jt = 0; jt < 4; ++jt){
      const u32 mj = (u32)(mw >> (jt * 16 + g4 * 4)) & 0xFu;
      #pragma unroll
      for (int r = 0; r < 4; ++r){
        float s = S[jt][r];
        s = ((mj >> r) & 1u) ? -1e30f : s;
        ps[jt*4+r] = s;
        cmax = fmaxf(cmax, s);
      }
      pmask |= mj << (jt * 4);
    }
    cmax = fmaxf(cmax, __shfl_xor(cmax, 16));
    cmax = fmaxf(cmax, __shfl_xor(cmax, 32));
    const float mnew = fmaxf(m_r, cmax);
    const float fac = __expf(m_r - mnew);   // branch-free
    m_r = mnew;
    float psum = 0.f;
    #pragma unroll
    for (int i = 0; i < 16; ++i){
      const float p = ((pmask >> i) & 1u) ? 0.f : __expf(ps[i] - mnew);
      ps[i] = p; psum += p;
    }
    psum += __shfl_xor(psum, 16);
    psum += __shfl_xor(psum, 32);
    l_r = l_r * fac + psum;

    // broadcast fac of rows g4*4+r (held at lanes 0..15) and rescale O
    float fr4[4];
    #pragma unroll
    for (int r = 0; r < 4; ++r) fr4[r] = __shfl(fac, g4 * 4 + r);
    #pragma unroll
    for (int dt = 0; dt < 4; ++dt){
      f32x4 tt = o[dt];
      tt[0] *= fr4[0]; tt[1] *= fr4[1]; tt[2] *= fr4[2]; tt[3] *= fr4[3];
      o[dt] = tt;
    }

    // --- P -> LDS: 4 consecutive keys per group -> b64 writes ---
    #pragma unroll
    for (int jt = 0; jt < 4; ++jt){
      ushort4 pk;
      pk.x = f2bfc(ps[jt*4+0]); pk.y = f2bfc(ps[jt*4+1]);
      pk.z = f2bfc(ps[jt*4+2]); pk.w = f2bfc(ps[jt*4+3]);
      *(ushort4*)ldsw(psb, l15, jt * 32 + g4 * 8) = pk;
    }

    // --- O += P V ---
    short8v pA[2];
    #pragma unroll
    for (int kc = 0; kc < 2; ++kc)
      pA[kc] = *(const short8v*)ldsw(psb, l15, kc * 64 + g4 * 16);
    char* Vc = (char*)&Vt[cur][0][0];
    #pragma unroll
    for (int dt = 0; dt < 4; ++dt){
      #pragma unroll
      for (int kc = 0; kc < 2; ++kc){
        const short8v vf = *(const short8v*)ldsw(Vc, dt*16 + l15, kc * 64 + g4 * 16);
        o[dt] = mfma16(pA[kc], vf, o[dt]);
      }
    }

    if (pf) writeV(cur ^ 1);
    __syncthreads();
  }

  const float linv = (l_r > 0.f) ? 1.0f / l_r : 0.f;
  float lr4[4];
  #pragma unroll
  for (int r = 0; r < 4; ++r) lr4[r] = __shfl(linv, g4 * 4 + r);
  #pragma unroll
  for (int dt = 0; dt < 4; ++dt)
    #pragma unroll
    for (int r = 0; r < 4; ++r)
      outp[(size_t)(b * TT + qb + wave * 16 + g4 * 4 + r) * CC + h * HD + dt * 16 + l15] =
          f2bf(o[dt][r] * lr4[r]);
}

// ---------------- launcher ----------------
extern "C" void kernel_launch(void* const* d_in, const int* in_sizes, int n_in,
                              void* d_out, int out_size, void* d_ws, size_t ws_size,
                              hipStream_t stream){
  (void)in_sizes; (void)n_in; (void)out_size; (void)ws_size;
  const float* pos    = (const float*)d_in[0];
  const float* coords = (const float*)d_in[1];
  const float* ln1g   = (const float*)d_in[2];
  const float* ln1b   = (const float*)d_in[3];
  const float* qkvw   = (const float*)d_in[4];
  const float* qkvbi  = (const float*)d_in[5];
  const float* outw   = (const float*)d_in[6];
  const float* outbi  = (const float*)d_in[7];
  const float* ln2g   = (const float*)d_in[8];
  const float* ln2b   = (const float*)d_in[9];
  const float* w1     = (const float*)d_in[10];
  const float* b1     = (const float*)d_in[11];
  const float* w2     = (const float*)d_in[12];
  const float* b2     = (const float*)d_in[13];
  const float* ng     = (const float*)d_in[14];
  const float* nbb    = (const float*)d_in[15];

  char* wsp = (char*)d_ws;
  size_t off = 0;
  auto alloc = [&](size_t bytes)->void*{
    void* p = wsp + off; off += (bytes + 255) & ~(size_t)255; return p;
  };
  u16* qkvw_bf = (u16*)alloc((size_t)NL*3*CC*CC*sizeof(u16));
  u16* outw_bf = (u16*)alloc((size_t)NL*CC*CC*sizeof(u16));
  u16* w1_bf   = (u16*)alloc((size_t)NL*4*CC*CC*sizeof(u16));
  u16* w2_bf   = (u16*)alloc((size_t)NL*4*CC*CC*sizeof(u16));
  float* x     = (float*)alloc((size_t)MM*CC*sizeof(float));
  u16* xn      = (u16*)alloc((size_t)MM*CC*sizeof(u16));
  u16* qkvbuf  = (u16*)alloc((size_t)MM*4*CC*sizeof(u16)); // reused as FFN hidden
  u16* attnb   = (u16*)alloc((size_t)MM*CC*sizeof(u16));
  u64* maskw   = (u64*)alloc((size_t)MM*24*sizeof(u64));
  u16* hbuf = qkvbuf;

  auto cvt = [&](const float* s, u16* dst, size_t n){
    int n4 = (int)(n >> 2);
    int blocks = (n4 + 255) / 256; if (blocks > 4096) blocks = 4096;
    cvt_bf16_kernel<<<dim3(blocks), dim3(256), 0, stream>>>(s, dst, n4);
  };
  cvt(qkvw, qkvw_bf, (size_t)NL*3*CC*CC);
  cvt(outw, outw_bf, (size_t)NL*CC*CC);
  cvt(w1, w1_bf, (size_t)NL*4*CC*CC);
  cvt(w2, w2_bf, (size_t)NL*4*CC*CC);

  hipMemcpyAsync(x, pos, (size_t)MM*CC*sizeof(float), hipMemcpyDeviceToDevice, stream);
  mask_kernel<<<dim3(MM/4), dim3(256), 0, stream>>>(coords, maskw);

  for (int l = 0; l < NL; ++l){
    ln_kernel<0><<<dim3(MM), dim3(256), 0, stream>>>(x, ln1g + l*CC, ln1b + l*CC, xn, nullptr);
    gemm_nt<0><<<dim3(3*CC/128, MM/128), dim3(512), 0, stream>>>(
        xn, qkvw_bf + (size_t)l*3*CC*CC, qkvbi + l*3*CC, nullptr, qkvbuf, nullptr, MM, 3*CC, CC);
    attn_kernel<<<dim3(TT/64, NB*NH), dim3(256), 0, stream>>>(qkvbuf, maskw, attnb);
    gemm_nt<2><<<dim3(CC/128, MM/128), dim3(512), 0, stream>>>(
        attnb, outw_bf + (size_t)l*CC*CC, outbi + l*CC, x, nullptr, x, MM, CC, CC);
    ln_kernel<0><<<dim3(MM), dim3(256), 0, stream>>>(x, ln2g + l*CC, ln2b + l*CC, xn, nullptr);
    gemm_nt<1><<<dim3(4*CC/128, MM/128), dim3(512), 0, stream>>>(
        xn, w1_bf + (size_t)l*4*CC*CC, b1 + l*4*CC, nullptr, hbuf, nullptr, MM, 4*CC, CC);
    gemm_nt<2><<<dim3(CC/128, MM/128), dim3(512), 0, stream>>>(
        hbuf, w2_bf + (size_t)l*4*CC*CC, b2 + l*CC, x, nullptr, x, MM, CC, 4*CC);
  }
  ln_kernel<1><<<dim3(MM), dim3(256), 0, stream>>>(x, ng, nbb, nullptr, (float*)d_out);
}

// Round 7
// 461.354 us; speedup vs baseline: 1.4479x; 1.0352x over previous
//
#include <hip/hip_runtime.h>

#define TT 1536
#define CC 1024
#define NH 16
#define HD 64
#define NL 2
#define NB 2
#define MM (NB*TT)  // 3072 rows total

typedef unsigned short u16;
typedef unsigned int u32;
typedef unsigned long long u64;
typedef __attribute__((ext_vector_type(8))) short short8v;
typedef __attribute__((ext_vector_type(4))) float f32x4;

__device__ __forceinline__ u16 f2bf(float f){
  u32 u = __float_as_uint(f);
  u32 r = (u + 0x7FFFu + ((u >> 16) & 1u)) >> 16;  // RNE
  return (u16)r;
}

__device__ __forceinline__ void gload_lds16(const void* g, void* l){
  __builtin_amdgcn_global_load_lds(
      (const __attribute__((address_space(1))) void*)g,
      (__attribute__((address_space(3))) void*)l, 16, 0, 0);
}

__device__ __forceinline__ f32x4 mfma16(short8v a, short8v b, f32x4 c){
  return __builtin_amdgcn_mfma_f32_16x16x32_bf16(a, b, c, 0, 0, 0);
}

__device__ __forceinline__ float exp2f_fast(float x){
  return __builtin_amdgcn_exp2f(x);   // v_exp_f32: D = 2^S0
}

__device__ __forceinline__ u32 cvt_pk_bf16(float lo, float hi){
  u32 r;
  asm("v_cvt_pk_bf16_f32 %0, %1, %2" : "=v"(r) : "v"(lo), "v"(hi));
  return r;
}

// XOR swizzle for 128B-row LDS tiles (64 x u16 per row).
__device__ __forceinline__ char* ldsw(void* base, int row, int colb){
  return (char*)base + row * 128 + (colb ^ ((row & 7) << 4));
}

// ---------------- f32 -> bf16 weight conversion ----------------
__global__ __launch_bounds__(256) void cvt_bf16_kernel(const float* __restrict__ in,
                                                       u16* __restrict__ out, int n4){
  int stride = gridDim.x * 256;
  for (int i = blockIdx.x * 256 + threadIdx.x; i < n4; i += stride){
    const float4 v = ((const float4*)in)[i];
    ushort4 o;
    o.x = f2bf(v.x); o.y = f2bf(v.y); o.z = f2bf(v.z); o.w = f2bf(v.w);
    ((ushort4*)out)[i] = o;
  }
}

// ---------------- mask precompute: 24 x u64 bit-words per row ----------------
__device__ __forceinline__ float fixc(float v){
  if (__builtin_isnan(v)) return 0.0f;
  if (__builtin_isinf(v)) return v > 0.0f ? 100.0f : -100.0f;
  return v;
}

__global__ __launch_bounds__(256) void mask_kernel(const float* __restrict__ coords,
                                                   u64* __restrict__ maskw){
  const int tid = threadIdx.x, wave = tid >> 6, lane = tid & 63;
  const int ri = blockIdx.x * 4 + wave;          // global row in [0, MM)
  const int b = ri / TT, i = ri - b * TT;
  const float* cp = coords + (size_t)ri * 3;
  const float cx = fixc(cp[0]), cy = fixc(cp[1]), cz = fixc(cp[2]);
  const int vi = i >> 8;                          // 256 tokens per view
  u64 allm = ~0ull;
  for (int ch = 0; ch < 24; ++ch){
    const int j = ch * 64 + lane;
    const float* cj = coords + ((size_t)b * TT + j) * 3;
    const float dx = cx - fixc(cj[0]);
    const float dy = cy - fixc(cj[1]);
    const float dz = cz - fixc(cj[2]);
    const float d2 = dx*dx + dy*dy + dz*dz;
    const bool masked = ((j >> 8) == vi) || (d2 > 100.0f);
    const u64 bal = __ballot(masked);
    if (lane == 0) maskw[(size_t)ri * 24 + ch] = bal;
    allm &= bal;
  }
  if (lane == 0 && allm == ~0ull){                // fully-masked row: unmask diagonal
    const size_t w = (size_t)ri * 24 + (i >> 6);
    maskw[w] &= ~(1ull << (i & 63));
  }
}

// ---------------- LayerNorm (f32 in -> bf16 or f32 out) ----------------
template<int OUTF>
__global__ __launch_bounds__(256) void ln_kernel(const float* __restrict__ x,
    const float* __restrict__ gw, const float* __restrict__ bw,
    u16* __restrict__ outb, float* __restrict__ outf){
  __shared__ float sred[4];
  const int tid = threadIdx.x, wave = tid >> 6, lane = tid & 63;
  const size_t row = blockIdx.x;
  const float4 v = *(const float4*)(x + row * CC + tid * 4);
  float s = v.x + v.y + v.z + v.w;
  #pragma unroll
  for (int o = 1; o < 64; o <<= 1) s += __shfl_xor(s, o, 64);
  if (lane == 0) sred[wave] = s;
  __syncthreads();
  const float mean = (sred[0] + sred[1] + sred[2] + sred[3]) * (1.0f / CC);
  __syncthreads();
  const float d0 = v.x - mean, d1 = v.y - mean, d2 = v.z - mean, d3 = v.w - mean;
  float q = d0*d0 + d1*d1 + d2*d2 + d3*d3;
  #pragma unroll
  for (int o = 1; o < 64; o <<= 1) q += __shfl_xor(q, o, 64);
  if (lane == 0) sred[wave] = q;
  __syncthreads();
  const float var = (sred[0] + sred[1] + sred[2] + sred[3]) * (1.0f / CC);
  const float rstd = rsqrtf(var + 1e-5f);
  const float4 g4 = *(const float4*)(gw + tid * 4);
  const float4 b4 = *(const float4*)(bw + tid * 4);
  const float y0 = d0 * rstd * g4.x + b4.x;
  const float y1 = d1 * rstd * g4.y + b4.y;
  const float y2 = d2 * rstd * g4.z + b4.z;
  const float y3 = d3 * rstd * g4.w + b4.w;
  if (OUTF){
    *(float4*)(outf + row * CC + tid * 4) = make_float4(y0, y1, y2, y3);
  } else {
    ushort4 o4; o4.x = f2bf(y0); o4.y = f2bf(y1); o4.z = f2bf(y2); o4.w = f2bf(y3);
    *(ushort4*)(outb + row * CC + tid * 4) = o4;
  }
}

// ---------------- NT GEMM v3: 128x128 tile, 8 waves, BK=64, double-buffered,
// counted-vmcnt 2-phase pipeline + T2 XOR-swizzled LDS ------------------------
// EPI 0: +bias -> bf16; EPI 1: +bias,gelu -> bf16; EPI 2: +bias +res -> f32
template<int EPI>
__global__ __launch_bounds__(512, 4) void gemm_nt(const u16* __restrict__ A,
    const u16* __restrict__ Bw, const float* __restrict__ bias,
    const float* __restrict__ res, u16* __restrict__ outb, float* __restrict__ outf,
    int M, int N, int K){
  __shared__ u16 As[2][128][64];
  __shared__ u16 Bs[2][128][64];
  const int tid = threadIdx.x, wave = tid >> 6, lane = tid & 63;
  // bijective XCD swizzle (m204)
  const int gx = gridDim.x;
  const int nwg = gx * gridDim.y;
  const int orig = blockIdx.y * gx + blockIdx.x;
  const int qq = nwg >> 3, rm = nwg & 7;
  const int xcd = orig & 7, pos = orig >> 3;
  const int wg = (xcd < rm ? xcd * (qq + 1) : rm * (qq + 1) + (xcd - rm) * qq) + pos;
  const int m0 = (wg / gx) * 128, n0 = (wg % gx) * 128;
  const int wr = wave >> 1, wc = wave & 1;   // 4x2 wave grid; per-wave out 32x64
  f32x4 acc[2][4];
  #pragma unroll
  for (int mi = 0; mi < 2; ++mi)
    #pragma unroll
    for (int ni = 0; ni < 4; ++ni){ f32x4 z = {0.f,0.f,0.f,0.f}; acc[mi][ni] = z; }

  const u16* Ag = A + (size_t)m0 * K;
  const u16* Bg = Bw + (size_t)n0 * K;
  const int srow0 = wave * 8 + (lane >> 3);
  const int scole = ((lane & 7) ^ (lane >> 3)) * 8;   // pre-swizzled source col
  auto stage = [&](int buf, int k0){
    char* ab = (char*)&As[buf][0][0];
    char* bb = (char*)&Bs[buf][0][0];
    #pragma unroll
    for (int l = 0; l < 2; ++l){
      const size_t goff = (size_t)(l*64 + srow0) * K + k0 + scole;
      const int loff = (l*8 + wave) * 1024;
      gload_lds16(Ag + goff, ab + loff);
      gload_lds16(Bg + goff, bb + loff);
    }
  };

  const int NT = K >> 6;
  stage(0, 0);
  stage(1, 64);

  const int ar = lane & 15, akb = (lane >> 4) * 16;
  const int rsw = (ar & 7) << 4;
  for (int t = 0; t < NT; ++t){
    const int cur = t & 1;
    if (t + 1 < NT) asm volatile("s_waitcnt vmcnt(4)" ::: "memory");
    else            asm volatile("s_waitcnt vmcnt(0)" ::: "memory");
    __builtin_amdgcn_s_barrier();
    const char* ab = (const char*)&As[cur][0][0];
    const char* bb = (const char*)&Bs[cur][0][0];
    short8v af[2][2], bf[4][2];
    #pragma unroll
    for (int ks = 0; ks < 2; ++ks){
      const int cb = (ks*64 + akb) ^ rsw;
      #pragma unroll
      for (int mi = 0; mi < 2; ++mi)
        af[mi][ks] = *(const short8v*)(ab + (wr*32 + mi*16 + ar)*128 + cb);
      #pragma unroll
      for (int ni = 0; ni < 4; ++ni)
        bf[ni][ks] = *(const short8v*)(bb + (wc*64 + ni*16 + ar)*128 + cb);
    }
    asm volatile("s_waitcnt lgkmcnt(0)" ::: "memory");
    __builtin_amdgcn_sched_barrier(0);
    __builtin_amdgcn_s_barrier();
    if (t + 2 < NT) stage(cur, (t + 2) * 64);
    __builtin_amdgcn_s_setprio(1);
    #pragma unroll
    for (int ks = 0; ks < 2; ++ks)
      #pragma unroll
      for (int mi = 0; mi < 2; ++mi)
        #pragma unroll
        for (int ni = 0; ni < 4; ++ni)
          acc[mi][ni] = mfma16(af[mi][ks], bf[ni][ks], acc[mi][ni]);
    __builtin_amdgcn_s_setprio(0);
  }

  const int cr = (lane >> 4) * 4, cl = lane & 15;
  #pragma unroll
  for (int ni = 0; ni < 4; ++ni){
    const int c = n0 + wc*64 + ni*16 + cl;
    const float bv = bias[c];
    #pragma unroll
    for (int mi = 0; mi < 2; ++mi){
      #pragma unroll
      for (int r = 0; r < 4; ++r){
        const size_t rr2 = (size_t)(m0 + wr*32 + mi*16 + cr + r);
        float v = acc[mi][ni][r] + bv;
        if constexpr (EPI == 1) v = 0.5f * v * (1.0f + erff(v * 0.70710678118654752f));
        if constexpr (EPI == 2) outf[rr2 * N + c] = v + res[rr2 * N + c];
        else outb[rr2 * N + c] = f2bf(v);
      }
    }
  }
}

// ---------------- Flash attention v3: swapped QK^T, exp2 softmax,
// defer-max rescale (T13), l-via-MFMA-ones, cvt_pk packing ----------------
__global__ __launch_bounds__(256) void attn_kernel(const u16* __restrict__ qkv,
    const u64* __restrict__ maskw, u16* __restrict__ outp){
  __shared__ u16 Ks[2][64][64];   // K chunk, swizzled rows
  __shared__ u16 Vt[2][64][64];   // V^T chunk [d][j], swizzled rows
  __shared__ u16 Ps[4][16][64];   // per-wave P tile [q_local][key], swizzled
  const int tid = threadIdx.x, wave = tid >> 6, lane = tid & 63;
  const int b = blockIdx.y >> 4, h = blockIdx.y & 15;
  const int qb = blockIdx.x * 64;
  const int rs = 3 * CC;
  const int g4 = lane >> 4;        // 0..3
  const int l15 = lane & 15;
  const int qrow = qb + wave * 16 + l15;

  // Q fragment, pre-scaled by 0.125*log2(e) so QK^T is in log2 units
  const float qscale = 0.18033688011112042f;
  const u16* qp = qkv + (size_t)(b * TT + qrow) * rs + h * HD + g4 * 8;
  short8v qf0, qf1;
  {
    const short8v r0 = *(const short8v*)qp;
    const short8v r1 = *(const short8v*)(qp + 32);
    #pragma unroll
    for (int e = 0; e < 8; ++e){
      qf0[e] = (short)f2bf(__uint_as_float(((u32)(u16)r0[e]) << 16) * qscale);
      qf1[e] = (short)f2bf(__uint_as_float(((u32)(u16)r1[e]) << 16) * qscale);
    }
  }

  f32x4 o[4], lacc;
  #pragma unroll
  for (int dt = 0; dt < 4; ++dt){ f32x4 z = {0.f,0.f,0.f,0.f}; o[dt] = z; }
  { f32x4 z = {0.f,0.f,0.f,0.f}; lacc = z; }
  float m_r = -1.0e4f;             // running max (log2 units), finite sentinel

  u16* psb = &Ps[wave][0][0];
  const u64* mrow_p = maskw + (size_t)(b * TT + qrow) * 24;

  // ones fragment for the l-accumulator MFMA (bf16 1.0 = 0x3F80)
  short8v vone;
  #pragma unroll
  for (int e = 0; e < 8; ++e) vone[e] = (short)0x3F80;

  auto stageK = [&](int t, int buf){
    const int j0 = t * 64;
    #pragma unroll
    for (int l = 0; l < 2; ++l){
      const int off = (wave * 2 + l) * 1024;             // wave-uniform
      const int krow = (off >> 7) + (lane >> 3);
      const int kcolb = ((lane & 7) * 16) ^ ((krow & 7) << 4);  // inverse-swizzled source
      gload_lds16(qkv + (size_t)(b * TT + j0 + krow) * rs + CC + h * HD + (kcolb >> 1),
                  (char*)(&Ks[buf][0][0]) + off);
    }
  };
  u16 vv[16];
  auto loadV = [&](int t){
    const int j0 = t * 64;
    #pragma unroll
    for (int it = 0; it < 2; ++it){
      const int jc = it * 4 + wave;
      #pragma unroll
      for (int e = 0; e < 8; ++e)
        vv[it*8+e] = qkv[(size_t)(b * TT + j0 + jc * 8 + e) * rs + 2 * CC + h * HD + lane];
    }
  };
  auto writeV = [&](int buf){
    #pragma unroll
    for (int it = 0; it < 2; ++it){
      const int jc = it * 4 + wave;
      short8v sv;
      #pragma unroll
      for (int e = 0; e < 8; ++e) sv[e] = (short)vv[it*8+e];
      *(short8v*)ldsw(&Vt[buf][0][0], lane, jc * 16) = sv;
    }
  };

  // prologue: stage chunk 0 into buf 0
  loadV(0);
  stageK(0, 0);
  writeV(0);
  __syncthreads();

  for (int t = 0; t < TT / 64; ++t){
    const int cur = t & 1;
    const bool pf = (t < TT / 64 - 1);
    if (pf){ loadV(t + 1); stageK(t + 1, cur ^ 1); }

    const u64 mw = mrow_p[t];
    const u32 mwlo = (u32)mw, mwhi = (u32)(mw >> 32);

    // --- S^T (log2 units): lane holds keys jt*16+g4*4+r of row q=qrow ---
    const char* Kc = (const char*)&Ks[cur][0][0];
    f32x4 S[4];
    #pragma unroll
    for (int jt = 0; jt < 4; ++jt){
      const short8v k0 = *(const short8v*)ldsw((void*)Kc, jt*16 + l15, g4 * 16);
      const short8v k1 = *(const short8v*)ldsw((void*)Kc, jt*16 + l15, 64 + g4 * 16);
      f32x4 z = {0.f,0.f,0.f,0.f};
      z = mfma16(k0, qf0, z);
      z = mfma16(k1, qf1, z);
      S[jt] = z;
    }

    // --- mask to -3e38 (exp2 underflows to 0; no separate zero-select) ---
    float ps[16];
    float cmax = -3.0e38f;
    #pragma unroll
    for (int jt = 0; jt < 4; ++jt){
      const u32 msrc = (jt & 2) ? mwhi : mwlo;
      const int sh = g4 * 4 + (jt & 1) * 16;
      #pragma unroll
      for (int r = 0; r < 4; ++r){
        float s = S[jt][r];
        s = ((msrc >> (sh + r)) & 1u) ? -3.0e38f : s;
        ps[jt*4+r] = s;
        cmax = fmaxf(cmax, s);
      }
    }
    cmax = fmaxf(cmax, __shfl_xor(cmax, 16));
    cmax = fmaxf(cmax, __shfl_xor(cmax, 32));

    // --- defer-max (T13): rescale only if some row grew past m_r + 8 ---
    if (!__all(cmax <= m_r + 8.0f)){
      const float mnew = fmaxf(m_r, cmax);
      const float fac = exp2f_fast(m_r - mnew);
      m_r = mnew;
      float fr4[4];
      #pragma unroll
      for (int r = 0; r < 4; ++r) fr4[r] = __shfl(fac, g4 * 4 + r);
      #pragma unroll
      for (int dt = 0; dt < 4; ++dt){
        f32x4 tt = o[dt];
        tt[0] *= fr4[0]; tt[1] *= fr4[1]; tt[2] *= fr4[2]; tt[3] *= fr4[3];
        o[dt] = tt;
      }
      lacc[0] *= fr4[0]; lacc[1] *= fr4[1]; lacc[2] *= fr4[2]; lacc[3] *= fr4[3];
    }

    // --- P = 2^(s - m); masked -> 0 by underflow ---
    #pragma unroll
    for (int i = 0; i < 16; ++i) ps[i] = exp2f_fast(ps[i] - m_r);

    // --- P -> LDS via packed bf16 converts ---
    #pragma unroll
    for (int jt = 0; jt < 4; ++jt){
      uint2 pk;
      pk.x = cvt_pk_bf16(ps[jt*4+0], ps[jt*4+1]);
      pk.y = cvt_pk_bf16(ps[jt*4+2], ps[jt*4+3]);
      *(uint2*)ldsw(psb, l15, jt * 32 + g4 * 8) = pk;
    }

    // --- O += P V ; l += P · 1 (row-sum via MFMA ones-column) ---
    short8v pA[2];
    #pragma unroll
    for (int kc = 0; kc < 2; ++kc)
      pA[kc] = *(const short8v*)ldsw(psb, l15, kc * 64 + g4 * 16);
    char* Vc = (char*)&Vt[cur][0][0];
    #pragma unroll
    for (int dt = 0; dt < 4; ++dt){
      #pragma unroll
      for (int kc = 0; kc < 2; ++kc){
        const short8v vf = *(const short8v*)ldsw(Vc, dt*16 + l15, kc * 64 + g4 * 16);
        o[dt] = mfma16(pA[kc], vf, o[dt]);
      }
    }
    lacc = mfma16(pA[0], vone, lacc);
    lacc = mfma16(pA[1], vone, lacc);

    if (pf) writeV(cur ^ 1);
    __syncthreads();
  }

  // lacc[r] and o[dt][r] share the same C/D row (q = g4*4+r): no shuffles
  float linv[4];
  #pragma unroll
  for (int r = 0; r < 4; ++r) linv[r] = 1.0f / fmaxf(lacc[r], 1e-30f);
  #pragma unroll
  for (int dt = 0; dt < 4; ++dt)
    #pragma unroll
    for (int r = 0; r < 4; ++r)
      outp[(size_t)(b * TT + qb + wave * 16 + g4 * 4 + r) * CC + h * HD + dt * 16 + l15] =
          f2bf(o[dt][r] * linv[r]);
}

// ---------------- launcher ----------------
extern "C" void kernel_launch(void* const* d_in, const int* in_sizes, int n_in,
                              void* d_out, int out_size, void* d_ws, size_t ws_size,
                              hipStream_t stream){
  (void)in_sizes; (void)n_in; (void)out_size; (void)ws_size;
  const float* pos    = (const float*)d_in[0];
  const float* coords = (const float*)d_in[1];
  const float* ln1g   = (const float*)d_in[2];
  const float* ln1b   = (const float*)d_in[3];
  const float* qkvw   = (const float*)d_in[4];
  const float* qkvbi  = (const float*)d_in[5];
  const float* outw   = (const float*)d_in[6];
  const float* outbi  = (const float*)d_in[7];
  const float* ln2g   = (const float*)d_in[8];
  const float* ln2b   = (const float*)d_in[9];
  const float* w1     = (const float*)d_in[10];
  const float* b1     = (const float*)d_in[11];
  const float* w2     = (const float*)d_in[12];
  const float* b2     = (const float*)d_in[13];
  const float* ng     = (const float*)d_in[14];
  const float* nbb    = (const float*)d_in[15];

  char* wsp = (char*)d_ws;
  size_t off = 0;
  auto alloc = [&](size_t bytes)->void*{
    void* p = wsp + off; off += (bytes + 255) & ~(size_t)255; return p;
  };
  u16* qkvw_bf = (u16*)alloc((size_t)NL*3*CC*CC*sizeof(u16));
  u16* outw_bf = (u16*)alloc((size_t)NL*CC*CC*sizeof(u16));
  u16* w1_bf   = (u16*)alloc((size_t)NL*4*CC*CC*sizeof(u16));
  u16* w2_bf   = (u16*)alloc((size_t)NL*4*CC*CC*sizeof(u16));
  float* x     = (float*)alloc((size_t)MM*CC*sizeof(float));
  u16* xn      = (u16*)alloc((size_t)MM*CC*sizeof(u16));
  u16* qkvbuf  = (u16*)alloc((size_t)MM*4*CC*sizeof(u16)); // reused as FFN hidden
  u16* attnb   = (u16*)alloc((size_t)MM*CC*sizeof(u16));
  u64* maskw   = (u64*)alloc((size_t)MM*24*sizeof(u64));
  u16* hbuf = qkvbuf;

  auto cvt = [&](const float* s, u16* dst, size_t n){
    int n4 = (int)(n >> 2);
    int blocks = (n4 + 255) / 256; if (blocks > 4096) blocks = 4096;
    cvt_bf16_kernel<<<dim3(blocks), dim3(256), 0, stream>>>(s, dst, n4);
  };
  cvt(qkvw, qkvw_bf, (size_t)NL*3*CC*CC);
  cvt(outw, outw_bf, (size_t)NL*CC*CC);
  cvt(w1, w1_bf, (size_t)NL*4*CC*CC);
  cvt(w2, w2_bf, (size_t)NL*4*CC*CC);

  hipMemcpyAsync(x, pos, (size_t)MM*CC*sizeof(float), hipMemcpyDeviceToDevice, stream);
  mask_kernel<<<dim3(MM/4), dim3(256), 0, stream>>>(coords, maskw);

  for (int l = 0; l < NL; ++l){
    ln_kernel<0><<<dim3(MM), dim3(256), 0, stream>>>(x, ln1g + l*CC, ln1b + l*CC, xn, nullptr);
    gemm_nt<0><<<dim3(3*CC/128, MM/128), dim3(512), 0, stream>>>(
        xn, qkvw_bf + (size_t)l*3*CC*CC, qkvbi + l*3*CC, nullptr, qkvbuf, nullptr, MM, 3*CC, CC);
    attn_kernel<<<dim3(TT/64, NB*NH), dim3(256), 0, stream>>>(qkvbuf, maskw, attnb);
    gemm_nt<2><<<dim3(CC/128, MM/128), dim3(512), 0, stream>>>(
        attnb, outw_bf + (size_t)l*CC*CC, outbi + l*CC, x, nullptr, x, MM, CC, CC);
    ln_kernel<0><<<dim3(MM), dim3(256), 0, stream>>>(x, ln2g + l*CC, ln2b + l*CC, xn, nullptr);
    gemm_nt<1><<<dim3(4*CC/128, MM/128), dim3(512), 0, stream>>>(
        xn, w1_bf + (size_t)l*4*CC*CC, b1 + l*4*CC, nullptr, hbuf, nullptr, MM, 4*CC, CC);
    gemm_nt<2><<<dim3(CC/128, MM/128), dim3(512), 0, stream>>>(
        hbuf, w2_bf + (size_t)l*4*CC*CC, b2 + l*CC, x, nullptr, x, MM, CC, 4*CC);
  }
  ln_kernel<1><<<dim3(MM), dim3(256), 0, stream>>>(x, ng, nbb, nullptr, (float*)d_out);
}